// Round 14
// baseline (2274.353 us; speedup 1.0000x reference)
//
#include <hip/hip_runtime.h>
#include <hip/hip_bf16.h>
#include <stdint.h>

#define NN 131072
#define NE 262144
#define DD 300
#define DP 320
#define D2 600
#define D2P 640
#define NL 5
#define BN_EPS 1e-5f

typedef __attribute__((ext_vector_type(8))) _Float16 f16x8;
typedef __attribute__((ext_vector_type(4))) float f32x4;
typedef __attribute__((ext_vector_type(4))) unsigned int uint4v;

static __device__ __forceinline__ float h2f(unsigned short u) {
    union { unsigned short u; _Float16 h; } c; c.u = u; return (float)c.h;
}
static __device__ __forceinline__ unsigned short f2h(float f) {
    union { unsigned short u; _Float16 h; } c; c.h = (_Float16)f; return c.u;
}

// ---------------- prep kernels ----------------

__global__ void k_w1t(const float* __restrict__ W1, unsigned short* __restrict__ W1t) {
    int idx = blockIdx.x * 256 + threadIdx.x;
    if (idx >= NL * D2P * DP) return;
    int l = idx / (D2P * DP);
    int r = idx % (D2P * DP);
    int n = r / DP, k = r % DP;
    float v = (n < D2 && k < DD) ? W1[(size_t)(l * DD + k) * D2 + n] : 0.f;
    W1t[idx] = f2h(v);
}

__global__ void k_w2t(const float* __restrict__ W2, unsigned short* __restrict__ W2t) {
    int idx = blockIdx.x * 256 + threadIdx.x;
    if (idx >= NL * DP * D2P) return;
    int l = idx / (DP * D2P);
    int r = idx % (DP * D2P);
    int n = r / D2P, k = r % D2P;
    float v = (n < DD && k < D2) ? W2[(size_t)(l * D2 + k) * DD + n] : 0.f;
    W2t[idx] = f2h(v);
}

__global__ void k_eec(const float* __restrict__ ee1, const float* __restrict__ ee2,
                      unsigned short* __restrict__ eec) {
    int idx = blockIdx.x * 256 + threadIdx.x;
    if (idx >= NL * 15 * DP) return;
    int l = idx / (15 * DP);
    int r = idx % (15 * DP);
    int cb = r / DP, c = r % DP;
    int b = cb / 3, d = cb % 3;
    float v = 0.f;
    if (c < DD) v = ee1[(size_t)(l * 5 + b) * DD + c] + ee2[(size_t)(l * 3 + d) * DD + c];
    eec[idx] = f2h(v);
}

__global__ void k_h0(const int* __restrict__ x, const float* __restrict__ xe1,
                     const float* __restrict__ xe2, unsigned short* __restrict__ h) {
    unsigned int idx = blockIdx.x * 256u + threadIdx.x;
    if (idx >= (unsigned int)NN * DP) return;
    unsigned int n = idx / DP, c = idx % DP;
    float v = 0.f;
    if (c < DD) v = xe1[(size_t)x[2 * n] * DD + c] + xe2[(size_t)x[2 * n + 1] * DD + c];
    h[idx] = f2h(v);
}

__global__ void k_ident(float* __restrict__ sc, float* __restrict__ sh) {
    int t = blockIdx.x * 256 + threadIdx.x;
    if (t < DP) { sc[t] = 1.f; sh[t] = 0.f; }
}

// ---------------- CSR build ----------------

__global__ void k_count(const int* __restrict__ ei, int* __restrict__ counts) {
    int e = blockIdx.x * 256 + threadIdx.x;
    if (e < NE) atomicAdd(&counts[ei[NE + e]], 1);
}

__global__ void k_scan1(const int* __restrict__ counts, int* __restrict__ partial) {
    __shared__ int sm[256];
    int t = threadIdx.x;
    sm[t] = counts[blockIdx.x * 256 + t];
    __syncthreads();
    for (int o = 128; o > 0; o >>= 1) {
        if (t < o) sm[t] += sm[t + o];
        __syncthreads();
    }
    if (t == 0) partial[blockIdx.x] = sm[0];
}

__global__ void k_scan2(const int* __restrict__ partial, int* __restrict__ partial2) {
    __shared__ int sm[512];
    int t = threadIdx.x;
    int v = partial[t];
    sm[t] = v;
    __syncthreads();
    for (int o = 1; o < 512; o <<= 1) {
        int add = (t >= o) ? sm[t - o] : 0;
        __syncthreads();
        sm[t] += add;
        __syncthreads();
    }
    partial2[t] = sm[t] - v;  // exclusive
}

__global__ void k_scan3(const int* __restrict__ counts, const int* __restrict__ partial2,
                        int* __restrict__ row_ptr, int* __restrict__ cursor) {
    __shared__ int sm[256];
    int t = threadIdx.x;
    int i = blockIdx.x * 256 + t;
    int v = counts[i];
    sm[t] = v;
    __syncthreads();
    for (int o = 1; o < 256; o <<= 1) {
        int add = (t >= o) ? sm[t - o] : 0;
        __syncthreads();
        sm[t] += add;
        __syncthreads();
    }
    int excl = partial2[blockIdx.x] + sm[t] - v;
    row_ptr[i] = excl;
    cursor[i] = excl;
    if (i == NN - 1) row_ptr[NN] = excl + v;
}

__global__ void k_fill(const int* __restrict__ ei, const int* __restrict__ ea,
                       int* __restrict__ cursor, int* __restrict__ srcs,
                       int* __restrict__ combos) {
    int e = blockIdx.x * 256 + threadIdx.x;
    if (e >= NE) return;
    int d = ei[NE + e];
    int pos = atomicAdd(&cursor[d], 1);
    srcs[pos] = ei[e];
    combos[pos] = ea[2 * e] * 3 + ea[2 * e + 1];
}

// ---------------- aggregation (pull, CSR) ----------------
__global__ void k_gather(const unsigned short* __restrict__ h, const float* __restrict__ sc,
                         const float* __restrict__ sh, int relu,
                         const int* __restrict__ row_ptr, const int* __restrict__ srcs,
                         const int* __restrict__ combos, const unsigned short* __restrict__ eec,
                         unsigned short* __restrict__ agg) {
    unsigned int idx = blockIdx.x * 256u + threadIdx.x;  // N*40 chunks of 8 cols
    if (idx >= (unsigned int)NN * 40) return;
    unsigned int m = idx / 40;
    unsigned int j = idx % 40;
    int c0 = j * 8;
    float a[8] = {0, 0, 0, 0, 0, 0, 0, 0};
    float scv[8], shv[8];
#pragma unroll
    for (int i = 0; i < 8; i++) { scv[i] = sc[c0 + i]; shv[i] = sh[c0 + i]; }
    int e0 = row_ptr[m], e1 = row_ptr[m + 1];
    for (int e = e0; e < e1; ++e) {
        int s = srcs[e], cb = combos[e];
        uint4v hv = *(const uint4v*)(h + (size_t)s * DP + c0);
        uint4v ev = *(const uint4v*)(eec + (size_t)cb * DP + c0);
        const unsigned short* hp = (const unsigned short*)&hv;
        const unsigned short* ep = (const unsigned short*)&ev;
#pragma unroll
        for (int i = 0; i < 8; i++) {
            float f = scv[i] * h2f(hp[i]) + shv[i];
            if (relu) f = fmaxf(f, 0.f);
            a[i] += f + h2f(ep[i]);
        }
    }
    unsigned short o[8];
#pragma unroll
    for (int i = 0; i < 8; i++) o[i] = f2h(a[i]);
    *(uint4v*)(agg + (size_t)m * DP + c0) = *(const uint4v*)o;
}

// ---------------- k_gemm_ar: round-4 structure, A-fragments read from GLOBAL ----------------
// C[M, n0..n0+319] = affine?(A)[M,K] @ B^T, grid (Nout/320, M/128), 512 thr, 8 waves (2m x 4n).
// B staged via global_load_lds into LDS (unchanged, pre-swizzled source). A is NOT staged:
// each wave loads its fragments directly from global in MFMA layout — 16 rows x 64B lines,
// fully line-coalesced; the 4 wn-waves of a wm-panel share lines via L1. Cuts LDS reads
// 144 -> 80 per block-kt (LDS pipe was the binding resource: 1728 cyc vs MFMA 1552).
// AFF=1 folds the BN1 affine+relu into the register fragments (scH/shH 16B loads, L1-hot).
#define TLD 328
template<int AFF>
__launch_bounds__(512, 2)
__global__ void k_gemm_ar(const unsigned short* __restrict__ A, int lda, int kIters,
                          const unsigned short* __restrict__ scH,
                          const unsigned short* __restrict__ shH,
                          const unsigned short* __restrict__ B,
                          unsigned short* __restrict__ C, int ldc,
                          float* __restrict__ stats, int statN) {
    __shared__ unsigned short smem[64 * TLD];  // Bs (320x64 = 40KB) ; reused as T[64][TLD]
    unsigned short* Bs = smem;
    int tid = threadIdx.x;
    int lane = tid & 63, wid = tid >> 6;
    int wm = wid >> 2, wn = wid & 3;
    int l15 = lane & 15, l4 = lane >> 4;
    int m0 = blockIdx.y * 128;
    int n0 = blockIdx.x * 320;
    const unsigned short* Bb = B + (size_t)n0 * lda;

    // B staging geometry (pre-swizzled global source, proven r4/dma geometry)
    int brow8 = lane >> 3;
    int bc16 = (lane & 7) ^ brow8;

    // per-lane A fragment row pointers (4 mf frags, rows wm*64+mf*16+l15)
    const unsigned short* aF[4];
#pragma unroll
    for (int mf = 0; mf < 4; ++mf)
        aF[mf] = A + (size_t)(m0 + wm * 64 + mf * 16 + l15) * lda;

    f32x4 acc[4][5] = {};

    for (int kt = 0; kt < kIters; ++kt) {
        int k0 = kt * 64;
        // B DMA: 5 chunks per wave (40 chunks = 320 rows x 64 cols)
#pragma unroll
        for (int j = 0; j < 5; ++j) {
            int chunk = wid * 5 + j;
            int n = chunk * 8 + brow8;
            const unsigned short* g = Bb + (size_t)n * lda + k0 + bc16 * 8;
            __builtin_amdgcn_global_load_lds(
                (const __attribute__((address_space(1))) unsigned int*)g,
                (__attribute__((address_space(3))) unsigned int*)&Bs[chunk * 512], 16, 0, 0);
        }
        __syncthreads();
#pragma unroll
        for (int ks = 0; ks < 2; ++ks) {
            int kf = k0 + (ks * 4 + l4) * 8;   // this lane's 8-element k-offset
            f16x8 af[4];
#pragma unroll
            for (int mf = 0; mf < 4; ++mf)
                af[mf] = *(const f16x8*)(aF[mf] + kf);
            if (AFF) {
                f16x8 sV = *(const f16x8*)&scH[kf];
                f16x8 hV = *(const f16x8*)&shH[kf];
#pragma unroll
                for (int mf = 0; mf < 4; ++mf) {
#pragma unroll
                    for (int i = 0; i < 8; ++i) {
                        _Float16 t = af[mf][i] * sV[i] + hV[i];
                        af[mf][i] = t > (_Float16)0 ? t : (_Float16)0;
                    }
                }
            }
#pragma unroll
            for (int nf = 0; nf < 5; ++nf) {
                int rb = wn * 80 + nf * 16 + l15;
                int c16 = (ks * 4 + l4) ^ (rb & 7);
                f16x8 bg = *(const f16x8*)&Bs[rb * 64 + c16 * 8];
#pragma unroll
                for (int mf = 0; mf < 4; ++mf)
                    acc[mf][nf] = __builtin_amdgcn_mfma_f32_16x16x32_f16(af[mf], bg, acc[mf][nf], 0, 0, 0);
            }
        }
        __syncthreads();
    }

    // ---- per-column stats (on f16-rounded values, matching stored C) ----
#pragma unroll
    for (int nf = 0; nf < 5; ++nf) {
        int col = n0 + wn * 80 + nf * 16 + l15;
        float s = 0.f, ss = 0.f;
#pragma unroll
        for (int mf = 0; mf < 4; ++mf) {
#pragma unroll
            for (int i = 0; i < 4; ++i) {
                float vr = h2f(f2h(acc[mf][nf][i]));
                s += vr;
                ss += vr * vr;
            }
        }
        s += __shfl_xor(s, 16); s += __shfl_xor(s, 32);
        ss += __shfl_xor(ss, 16); ss += __shfl_xor(ss, 32);
        if (lane < 16) {
            atomicAdd(&stats[col], s);
            atomicAdd(&stats[statN + col], ss);
        }
    }

    // ---- LDS-transpose epilogue: coalesced row-major stores (r4-proven) ----
    unsigned short* T = smem;  // 64 x TLD f16 = 41 KB
#pragma unroll
    for (int half = 0; half < 2; ++half) {
        __syncthreads();
        if (wm == half) {
#pragma unroll
            for (int nf = 0; nf < 5; ++nf) {
                int col = wn * 80 + nf * 16 + l15;
#pragma unroll
                for (int mf = 0; mf < 4; ++mf) {
                    int r = mf * 16 + (l4 << 2);
#pragma unroll
                    for (int i = 0; i < 4; ++i)
                        T[(r + i) * TLD + col] = f2h(acc[mf][nf][i]);
                }
            }
        }
        __syncthreads();
        int rowbase = m0 + half * 64;
#pragma unroll
        for (int p = 0; p < 5; ++p) {
            int cid = p * 512 + tid;          // 0..2559
            int r = cid / 40, c16 = cid % 40;
            uint4v v = *(const uint4v*)&T[r * TLD + c16 * 8];
            *(uint4v*)&C[(size_t)(rowbase + r) * ldc + n0 + c16 * 8] = v;
        }
    }
}

// ---------------- BN scale/shift from stats (f32 + f16 copies) ----------------
__global__ void k_bnprep(const float* __restrict__ stats, int statN, int realN,
                         const float* __restrict__ g, const float* __restrict__ b,
                         float* __restrict__ sc, float* __restrict__ sh,
                         unsigned short* __restrict__ scH, unsigned short* __restrict__ shH) {
    int n = blockIdx.x * 256 + threadIdx.x;
    if (n >= statN) return;
    float scv = 0.f, shv = 0.f;
    if (n < realN) {
        float mu = stats[n] * (1.f / NN);
        float var = stats[statN + n] * (1.f / NN) - mu * mu;
        var = fmaxf(var, 0.f);
        float rs = rsqrtf(var + BN_EPS);
        scv = g[n] * rs;
        shv = b[n] - mu * scv;
    }
    sc[n] = scv;
    sh[n] = shv;
    scH[n] = f2h(scv);
    shH[n] = f2h(shv);
}

// ---------------- final output ----------------
__global__ void k_out(const unsigned short* __restrict__ u2, const float* __restrict__ sc,
                      const float* __restrict__ sh, float* __restrict__ out) {
    unsigned int idx = blockIdx.x * 256u + threadIdx.x;
    if (idx >= (unsigned int)NN * DD) return;
    unsigned int n = idx / DD, d = idx % DD;
    out[idx] = sc[d] * h2f(u2[(size_t)n * DP + d]) + sh[d];
}

extern "C" void kernel_launch(void* const* d_in, const int* in_sizes, int n_in,
                              void* d_out, int out_size, void* d_ws, size_t ws_size,
                              hipStream_t stream) {
    const int* x = (const int*)d_in[0];
    const int* ei = (const int*)d_in[1];
    const int* ea = (const int*)d_in[2];
    const float* xe1 = (const float*)d_in[3];
    const float* xe2 = (const float*)d_in[4];
    const float* ee1 = (const float*)d_in[5];
    const float* ee2 = (const float*)d_in[6];
    const float* W1 = (const float*)d_in[7];
    const float* bn1g = (const float*)d_in[9];
    const float* bn1b = (const float*)d_in[10];
    const float* W2 = (const float*)d_in[11];
    const float* bng = (const float*)d_in[13];
    const float* bnb = (const float*)d_in[14];
    float* out = (float*)d_out;

    char* ws = (char*)d_ws;
    size_t off = 0;
    auto alloc = [&](size_t bytes) -> void* {
        void* p = ws + off;
        off += (bytes + 255) & ~(size_t)255;
        return p;
    };
    unsigned short* hbuf = (unsigned short*)alloc((size_t)NN * DP * 2);   // h0 / u2
    unsigned short* agg  = (unsigned short*)alloc((size_t)NN * DP * 2);
    unsigned short* u1   = (unsigned short*)alloc((size_t)NN * D2P * 2);
    unsigned short* W1t  = (unsigned short*)alloc((size_t)NL * D2P * DP * 2);
    unsigned short* W2t  = (unsigned short*)alloc((size_t)NL * DP * D2P * 2);
    unsigned short* eec  = (unsigned short*)alloc((size_t)NL * 15 * DP * 2);
    int* row_ptr = (int*)alloc((size_t)(NN + 1) * 4);
    int* cursor  = (int*)alloc((size_t)NN * 4);
    int* counts  = (int*)alloc((size_t)NN * 4);
    int* srcs    = (int*)alloc((size_t)NE * 4);
    int* combos  = (int*)alloc((size_t)NE * 4);
    int* partial  = (int*)alloc(512 * 4);
    int* partial2 = (int*)alloc(512 * 4);
    float* stats1 = (float*)alloc(2 * D2P * 4);
    float* stats2 = (float*)alloc(2 * DP * 4);
    float* sc1 = (float*)alloc(D2P * 4);
    float* sh1 = (float*)alloc(D2P * 4);
    float* sc2 = (float*)alloc(DP * 4);
    float* sh2 = (float*)alloc(DP * 4);
    float* sc0 = (float*)alloc(DP * 4);
    float* sh0 = (float*)alloc(DP * 4);
    unsigned short* scH1 = (unsigned short*)alloc(D2P * 2);
    unsigned short* shH1 = (unsigned short*)alloc(D2P * 2);
    unsigned short* scH2 = (unsigned short*)alloc(DP * 2);
    unsigned short* shH2 = (unsigned short*)alloc(DP * 2);

    // prep
    k_w1t<<<NL * D2P * DP / 256, 256, 0, stream>>>(W1, W1t);
    k_w2t<<<NL * DP * D2P / 256, 256, 0, stream>>>(W2, W2t);
    k_eec<<<(NL * 15 * DP + 255) / 256, 256, 0, stream>>>(ee1, ee2, eec);
    k_h0<<<NN * DP / 256, 256, 0, stream>>>(x, xe1, xe2, hbuf);
    k_ident<<<2, 256, 0, stream>>>(sc0, sh0);

    // CSR
    hipMemsetAsync(counts, 0, (size_t)NN * 4, stream);
    k_count<<<NE / 256, 256, 0, stream>>>(ei, counts);
    k_scan1<<<NN / 256, 256, 0, stream>>>(counts, partial);
    k_scan2<<<1, 512, 0, stream>>>(partial, partial2);
    k_scan3<<<NN / 256, 256, 0, stream>>>(counts, partial2, row_ptr, cursor);
    k_fill<<<NE / 256, 256, 0, stream>>>(ei, ea, cursor, srcs, combos);

    const unsigned short* hcur = hbuf;
    const float* scIn = sc0;
    const float* shIn = sh0;
    int reluIn = 0;
    for (int l = 0; l < NL; ++l) {
        k_gather<<<NN * 40 / 256, 256, 0, stream>>>(hcur, scIn, shIn, reluIn, row_ptr, srcs,
                                                    combos, eec + (size_t)l * 15 * DP, agg);
        hipMemsetAsync(stats1, 0, 2 * D2P * 4, stream);
        dim3 g1(D2P / 320, NN / 128);
        k_gemm_ar<0><<<g1, 512, 0, stream>>>(agg, DP, DP / 64, nullptr, nullptr,
                                             W1t + (size_t)l * D2P * DP, u1, D2P, stats1, D2P);
        k_bnprep<<<(D2P + 255) / 256, 256, 0, stream>>>(stats1, D2P, D2, bn1g + (size_t)l * D2,
                                                        bn1b + (size_t)l * D2, sc1, sh1, scH1, shH1);
        hipMemsetAsync(stats2, 0, 2 * DP * 4, stream);
        dim3 g2(DP / 320, NN / 128);
        k_gemm_ar<1><<<g2, 512, 0, stream>>>(u1, D2P, D2P / 64, scH1, shH1,
                                             W2t + (size_t)l * DP * D2P, hbuf, DP, stats2, DP);
        k_bnprep<<<(DP + 255) / 256, 256, 0, stream>>>(stats2, DP, DD, bng + (size_t)l * DD,
                                                       bnb + (size_t)l * DD, sc2, sh2, scH2, shH2);
        hcur = hbuf;
        scIn = sc2;
        shIn = sh2;
        reluIn = 1;
    }
    k_out<<<(unsigned int)NN * DD / 256, 256, 0, stream>>>(hbuf, sc2, sh2, out);
}

// Round 17
// 1894.154 us; speedup vs baseline: 1.2007x; 1.2007x over previous
//
#include <hip/hip_runtime.h>
#include <hip/hip_bf16.h>
#include <stdint.h>

#define NN 131072
#define NE 262144
#define DD 300
#define DP 320
#define D2 600
#define D2P 640
#define NL 5
#define BN_EPS 1e-5f

typedef __attribute__((ext_vector_type(8))) _Float16 f16x8;
typedef __attribute__((ext_vector_type(4))) float f32x4;
typedef __attribute__((ext_vector_type(4))) unsigned int uint4v;

static __device__ __forceinline__ float h2f(unsigned short u) {
    union { unsigned short u; _Float16 h; } c; c.u = u; return (float)c.h;
}
static __device__ __forceinline__ unsigned short f2h(float f) {
    union { unsigned short u; _Float16 h; } c; c.h = (_Float16)f; return c.u;
}

// ---------------- prep kernels ----------------

__global__ void k_w1t(const float* __restrict__ W1, unsigned short* __restrict__ W1t) {
    int idx = blockIdx.x * 256 + threadIdx.x;
    if (idx >= NL * D2P * DP) return;
    int l = idx / (D2P * DP);
    int r = idx % (D2P * DP);
    int n = r / DP, k = r % DP;
    float v = (n < D2 && k < DD) ? W1[(size_t)(l * DD + k) * D2 + n] : 0.f;
    W1t[idx] = f2h(v);
}

__global__ void k_w2t(const float* __restrict__ W2, unsigned short* __restrict__ W2t) {
    int idx = blockIdx.x * 256 + threadIdx.x;
    if (idx >= NL * DP * D2P) return;
    int l = idx / (DP * D2P);
    int r = idx % (DP * D2P);
    int n = r / D2P, k = r % D2P;
    float v = (n < DD && k < D2) ? W2[(size_t)(l * D2 + k) * DD + n] : 0.f;
    W2t[idx] = f2h(v);
}

__global__ void k_eec(const float* __restrict__ ee1, const float* __restrict__ ee2,
                      unsigned short* __restrict__ eec) {
    int idx = blockIdx.x * 256 + threadIdx.x;
    if (idx >= NL * 15 * DP) return;
    int l = idx / (15 * DP);
    int r = idx % (15 * DP);
    int cb = r / DP, c = r % DP;
    int b = cb / 3, d = cb % 3;
    float v = 0.f;
    if (c < DD) v = ee1[(size_t)(l * 5 + b) * DD + c] + ee2[(size_t)(l * 3 + d) * DD + c];
    eec[idx] = f2h(v);
}

__global__ void k_h0(const int* __restrict__ x, const float* __restrict__ xe1,
                     const float* __restrict__ xe2, unsigned short* __restrict__ h) {
    unsigned int idx = blockIdx.x * 256u + threadIdx.x;
    if (idx >= (unsigned int)NN * DP) return;
    unsigned int n = idx / DP, c = idx % DP;
    float v = 0.f;
    if (c < DD) v = xe1[(size_t)x[2 * n] * DD + c] + xe2[(size_t)x[2 * n + 1] * DD + c];
    h[idx] = f2h(v);
}

__global__ void k_ident(float* __restrict__ sc, float* __restrict__ sh) {
    int t = blockIdx.x * 256 + threadIdx.x;
    if (t < DP) { sc[t] = 1.f; sh[t] = 0.f; }
}

// ---------------- CSR build ----------------

__global__ void k_count(const int* __restrict__ ei, int* __restrict__ counts) {
    int e = blockIdx.x * 256 + threadIdx.x;
    if (e < NE) atomicAdd(&counts[ei[NE + e]], 1);
}

__global__ void k_scan1(const int* __restrict__ counts, int* __restrict__ partial) {
    __shared__ int sm[256];
    int t = threadIdx.x;
    sm[t] = counts[blockIdx.x * 256 + t];
    __syncthreads();
    for (int o = 128; o > 0; o >>= 1) {
        if (t < o) sm[t] += sm[t + o];
        __syncthreads();
    }
    if (t == 0) partial[blockIdx.x] = sm[0];
}

__global__ void k_scan2(const int* __restrict__ partial, int* __restrict__ partial2) {
    __shared__ int sm[512];
    int t = threadIdx.x;
    int v = partial[t];
    sm[t] = v;
    __syncthreads();
    for (int o = 1; o < 512; o <<= 1) {
        int add = (t >= o) ? sm[t - o] : 0;
        __syncthreads();
        sm[t] += add;
        __syncthreads();
    }
    partial2[t] = sm[t] - v;  // exclusive
}

__global__ void k_scan3(const int* __restrict__ counts, const int* __restrict__ partial2,
                        int* __restrict__ row_ptr, int* __restrict__ cursor) {
    __shared__ int sm[256];
    int t = threadIdx.x;
    int i = blockIdx.x * 256 + t;
    int v = counts[i];
    sm[t] = v;
    __syncthreads();
    for (int o = 1; o < 256; o <<= 1) {
        int add = (t >= o) ? sm[t - o] : 0;
        __syncthreads();
        sm[t] += add;
        __syncthreads();
    }
    int excl = partial2[blockIdx.x] + sm[t] - v;
    row_ptr[i] = excl;
    cursor[i] = excl;
    if (i == NN - 1) row_ptr[NN] = excl + v;
}

__global__ void k_fill(const int* __restrict__ ei, const int* __restrict__ ea,
                       int* __restrict__ cursor, int* __restrict__ srcs,
                       int* __restrict__ combos) {
    int e = blockIdx.x * 256 + threadIdx.x;
    if (e >= NE) return;
    int d = ei[NE + e];
    int pos = atomicAdd(&cursor[d], 1);
    srcs[pos] = ei[e];
    combos[pos] = ea[2 * e] * 3 + ea[2 * e + 1];
}

// ---------------- aggregation (pull, CSR) ----------------
__global__ void k_gather(const unsigned short* __restrict__ h, const float* __restrict__ sc,
                         const float* __restrict__ sh, int relu,
                         const int* __restrict__ row_ptr, const int* __restrict__ srcs,
                         const int* __restrict__ combos, const unsigned short* __restrict__ eec,
                         unsigned short* __restrict__ agg) {
    unsigned int idx = blockIdx.x * 256u + threadIdx.x;  // N*40 chunks of 8 cols
    if (idx >= (unsigned int)NN * 40) return;
    unsigned int m = idx / 40;
    unsigned int j = idx % 40;
    int c0 = j * 8;
    float a[8] = {0, 0, 0, 0, 0, 0, 0, 0};
    float scv[8], shv[8];
#pragma unroll
    for (int i = 0; i < 8; i++) { scv[i] = sc[c0 + i]; shv[i] = sh[c0 + i]; }
    int e0 = row_ptr[m], e1 = row_ptr[m + 1];
    for (int e = e0; e < e1; ++e) {
        int s = srcs[e], cb = combos[e];
        uint4v hv = *(const uint4v*)(h + (size_t)s * DP + c0);
        uint4v ev = *(const uint4v*)(eec + (size_t)cb * DP + c0);
        const unsigned short* hp = (const unsigned short*)&hv;
        const unsigned short* ep = (const unsigned short*)&ev;
#pragma unroll
        for (int i = 0; i < 8; i++) {
            float f = scv[i] * h2f(hp[i]) + shv[i];
            if (relu) f = fmaxf(f, 0.f);
            a[i] += f + h2f(ep[i]);
        }
    }
    unsigned short o[8];
#pragma unroll
    for (int i = 0; i < 8; i++) o[i] = f2h(a[i]);
    *(uint4v*)(agg + (size_t)m * DP + c0) = *(const uint4v*)o;
}

// ---------------- k_gemm_r4: EXACT round-4 GEMM (142 us/dispatch anchor) ----------------
#define TLD 328
__launch_bounds__(512, 2)
__global__ void k_gemm_r4(const unsigned short* __restrict__ A, int lda, int kIters,
                          const unsigned short* __restrict__ scH,
                          const unsigned short* __restrict__ shH,
                          const unsigned short* __restrict__ B,
                          unsigned short* __restrict__ C, int ldc,
                          float* __restrict__ stats, int statN) {
    __shared__ unsigned short smem[128 * 64 + 320 * 64];
    unsigned short* As = smem;
    unsigned short* Bs = smem + 128 * 64;
    int tid = threadIdx.x;
    int lane = tid & 63, wid = tid >> 6;
    int wm = wid >> 2, wn = wid & 3;
    int m0 = blockIdx.y * 128;
    int n0 = blockIdx.x * 320;
    const unsigned short* Bb = B + (size_t)n0 * lda;

    int srow = tid >> 2;
    int sc16 = tid & 3;
    int swz = srow & 7;
    const unsigned short* aRow = A + (size_t)(m0 + srow) * lda;
    int brow8 = lane >> 3;
    int bc16 = (lane & 7) ^ brow8;

    f32x4 acc[4][5] = {};

    for (int kt = 0; kt < kIters; ++kt) {
        int k0 = kt * 64;
#pragma unroll
        for (int j = 0; j < 5; ++j) {
            int chunk = wid * 5 + j;
            int n = chunk * 8 + brow8;
            const unsigned short* g = Bb + (size_t)n * lda + k0 + bc16 * 8;
            __builtin_amdgcn_global_load_lds(
                (const __attribute__((address_space(1))) unsigned int*)g,
                (__attribute__((address_space(3))) unsigned int*)&Bs[chunk * 512], 16, 0, 0);
        }
        uint4v v0 = *(const uint4v*)(aRow + k0 + sc16 * 8);
        uint4v v1 = *(const uint4v*)(aRow + k0 + (sc16 + 4) * 8);
        if (scH) {
            f16x8 a0 = *(f16x8*)&v0, a1 = *(f16x8*)&v1;
            f16x8 s0 = *(const f16x8*)&scH[k0 + sc16 * 8];
            f16x8 h0 = *(const f16x8*)&shH[k0 + sc16 * 8];
            f16x8 s1 = *(const f16x8*)&scH[k0 + (sc16 + 4) * 8];
            f16x8 h1 = *(const f16x8*)&shH[k0 + (sc16 + 4) * 8];
#pragma unroll
            for (int i = 0; i < 8; i++) {
                _Float16 t0 = a0[i] * s0[i] + h0[i];
                _Float16 t1 = a1[i] * s1[i] + h1[i];
                a0[i] = t0 > (_Float16)0 ? t0 : (_Float16)0;
                a1[i] = t1 > (_Float16)0 ? t1 : (_Float16)0;
            }
            v0 = *(uint4v*)&a0;
            v1 = *(uint4v*)&a1;
        }
        *(uint4v*)&As[srow * 64 + ((sc16 ^ swz) * 8)] = v0;
        *(uint4v*)&As[srow * 64 + (((sc16 + 4) ^ swz) * 8)] = v1;
        __syncthreads();
#pragma unroll
        for (int ks = 0; ks < 2; ++ks) {
            f16x8 af[4];
#pragma unroll
            for (int mf = 0; mf < 4; ++mf) {
                int ra = wm * 64 + mf * 16 + (lane & 15);
                int c16 = (ks * 4 + (lane >> 4)) ^ (ra & 7);
                af[mf] = *(const f16x8*)&As[ra * 64 + c16 * 8];
            }
#pragma unroll
            for (int nf = 0; nf < 5; ++nf) {
                int rb = wn * 80 + nf * 16 + (lane & 15);
                int c16 = (ks * 4 + (lane >> 4)) ^ (rb & 7);
                f16x8 bg = *(const f16x8*)&Bs[rb * 64 + c16 * 8];
#pragma unroll
                for (int mf = 0; mf < 4; ++mf)
                    acc[mf][nf] = __builtin_amdgcn_mfma_f32_16x16x32_f16(af[mf], bg, acc[mf][nf], 0, 0, 0);
            }
        }
        __syncthreads();
    }

#pragma unroll
    for (int nf = 0; nf < 5; ++nf) {
        int col = n0 + wn * 80 + nf * 16 + (lane & 15);
        float s = 0.f, ss = 0.f;
#pragma unroll
        for (int mf = 0; mf < 4; ++mf) {
#pragma unroll
            for (int i = 0; i < 4; ++i) {
                float vr = h2f(f2h(acc[mf][nf][i]));
                s += vr;
                ss += vr * vr;
            }
        }
        s += __shfl_xor(s, 16); s += __shfl_xor(s, 32);
        ss += __shfl_xor(ss, 16); ss += __shfl_xor(ss, 32);
        if (lane < 16) {
            atomicAdd(&stats[col], s);
            atomicAdd(&stats[statN + col], ss);
        }
    }

    unsigned short* T = smem;
#pragma unroll
    for (int half = 0; half < 2; ++half) {
        __syncthreads();
        if (wm == half) {
#pragma unroll
            for (int nf = 0; nf < 5; ++nf) {
                int col = wn * 80 + nf * 16 + (lane & 15);
#pragma unroll
                for (int mf = 0; mf < 4; ++mf) {
                    int r = mf * 16 + ((lane >> 4) << 2);
#pragma unroll
                    for (int i = 0; i < 4; ++i)
                        T[(r + i) * TLD + col] = f2h(acc[mf][nf][i]);
                }
            }
        }
        __syncthreads();
        int rowbase = m0 + half * 64;
#pragma unroll
        for (int p = 0; p < 5; ++p) {
            int cid = p * 512 + tid;
            int r = cid / 40, c16 = cid % 40;
            uint4v v = *(const uint4v*)&T[r * TLD + c16 * 8];
            *(uint4v*)&C[(size_t)(rowbase + r) * ldc + n0 + c16 * 8] = v;
        }
    }
}

// ---------------- k_gemm_dma: r4 structure, A via global_load_lds (142 us control) ----------------
__launch_bounds__(512, 2)
__global__ void k_gemm_dma(const unsigned short* __restrict__ A, int lda, int kIters,
                           const unsigned short* __restrict__ B,
                           unsigned short* __restrict__ C, int ldc,
                           float* __restrict__ stats, int statN) {
    __shared__ unsigned short smem[128 * 64 + 320 * 64];
    unsigned short* As = smem;
    unsigned short* Bs = smem + 128 * 64;
    int tid = threadIdx.x;
    int lane = tid & 63, wid = tid >> 6;
    int wm = wid >> 2, wn = wid & 3;
    int m0 = blockIdx.y * 128;
    int n0 = blockIdx.x * 320;
    const unsigned short* Bb = B + (size_t)n0 * lda;
    const unsigned short* Ab = A + (size_t)m0 * lda;

    int brow8 = lane >> 3;
    int bc16 = (lane & 7) ^ brow8;

    f32x4 acc[4][5] = {};

    for (int kt = 0; kt < kIters; ++kt) {
        int k0 = kt * 64;
#pragma unroll
        for (int j = 0; j < 5; ++j) {
            int chunk = wid * 5 + j;
            int n = chunk * 8 + brow8;
            const unsigned short* g = Bb + (size_t)n * lda + k0 + bc16 * 8;
            __builtin_amdgcn_global_load_lds(
                (const __attribute__((address_space(1))) unsigned int*)g,
                (__attribute__((address_space(3))) unsigned int*)&Bs[chunk * 512], 16, 0, 0);
        }
#pragma unroll
        for (int j = 0; j < 2; ++j) {
            int chunk = wid * 2 + j;
            int row = chunk * 8 + brow8;
            const unsigned short* g = Ab + (size_t)row * lda + k0 + bc16 * 8;
            __builtin_amdgcn_global_load_lds(
                (const __attribute__((address_space(1))) unsigned int*)g,
                (__attribute__((address_space(3))) unsigned int*)&As[chunk * 512], 16, 0, 0);
        }
        __syncthreads();
#pragma unroll
        for (int ks = 0; ks < 2; ++ks) {
            f16x8 af[4];
#pragma unroll
            for (int mf = 0; mf < 4; ++mf) {
                int ra = wm * 64 + mf * 16 + (lane & 15);
                int c16 = (ks * 4 + (lane >> 4)) ^ (ra & 7);
                af[mf] = *(const f16x8*)&As[ra * 64 + c16 * 8];
            }
#pragma unroll
            for (int nf = 0; nf < 5; ++nf) {
                int rb = wn * 80 + nf * 16 + (lane & 15);
                int c16 = (ks * 4 + (lane >> 4)) ^ (rb & 7);
                f16x8 bg = *(const f16x8*)&Bs[rb * 64 + c16 * 8];
#pragma unroll
                for (int mf = 0; mf < 4; ++mf)
                    acc[mf][nf] = __builtin_amdgcn_mfma_f32_16x16x32_f16(af[mf], bg, acc[mf][nf], 0, 0, 0);
            }
        }
        __syncthreads();
    }

#pragma unroll
    for (int nf = 0; nf < 5; ++nf) {
        int col = n0 + wn * 80 + nf * 16 + (lane & 15);
        float s = 0.f, ss = 0.f;
#pragma unroll
        for (int mf = 0; mf < 4; ++mf) {
#pragma unroll
            for (int i = 0; i < 4; ++i) {
                float vr = h2f(f2h(acc[mf][nf][i]));
                s += vr;
                ss += vr * vr;
            }
        }
        s += __shfl_xor(s, 16); s += __shfl_xor(s, 32);
        ss += __shfl_xor(ss, 16); ss += __shfl_xor(ss, 32);
        if (lane < 16) {
            atomicAdd(&stats[col], s);
            atomicAdd(&stats[statN + col], ss);
        }
    }

    unsigned short* T = smem;
#pragma unroll
    for (int half = 0; half < 2; ++half) {
        __syncthreads();
        if (wm == half) {
#pragma unroll
            for (int nf = 0; nf < 5; ++nf) {
                int col = wn * 80 + nf * 16 + (lane & 15);
#pragma unroll
                for (int mf = 0; mf < 4; ++mf) {
                    int r = mf * 16 + ((lane >> 4) << 2);
#pragma unroll
                    for (int i = 0; i < 4; ++i)
                        T[(r + i) * TLD + col] = f2h(acc[mf][nf][i]);
                }
            }
        }
        __syncthreads();
        int rowbase = m0 + half * 64;
#pragma unroll
        for (int p = 0; p < 5; ++p) {
            int cid = p * 512 + tid;
            int r = cid / 40, c16 = cid % 40;
            uint4v v = *(const uint4v*)&T[r * TLD + c16 * 8];
            *(uint4v*)&C[(size_t)(rowbase + r) * ldc + n0 + c16 * 8] = v;
        }
    }
}

// ---------------- k_gemm_b160: BM=128, BN=160, DMA-A, 36 KB LDS -> 3-4 blocks/CU ----------------
// Waves 4m x 2n (wave tile 32x80), acc[2][5] = 40 VGPR. No min-wave launch bound (r6's
// confound was the (512,4) VGPR squeeze). grid = (Nout/160, NN/128).
#define TLDB 168
__global__ void __launch_bounds__(512)
k_gemm_b160(const unsigned short* __restrict__ A, int lda, int kIters,
            const unsigned short* __restrict__ B,
            unsigned short* __restrict__ C, int ldc,
            float* __restrict__ stats, int statN) {
    __shared__ unsigned short smem[128 * 64 + 160 * 64];  // As | Bs ; T[32][168] reuses
    unsigned short* As = smem;
    unsigned short* Bs = smem + 128 * 64;
    int tid = threadIdx.x;
    int lane = tid & 63, wid = tid >> 6;
    int wm = wid >> 1, wn = wid & 1;   // 4m x 2n
    int l15 = lane & 15, l4 = lane >> 4;
    int m0 = blockIdx.y * 128;
    int n0 = blockIdx.x * 160;
    const unsigned short* Bb = B + (size_t)n0 * lda;
    const unsigned short* Ab = A + (size_t)m0 * lda;

    int brow8 = lane >> 3;
    int bc16 = (lane & 7) ^ brow8;

    f32x4 acc[2][5] = {};

    for (int kt = 0; kt < kIters; ++kt) {
        int k0 = kt * 64;
        // B DMA: 20 chunks (160 rows)
        for (int chunk = wid; chunk < 20; chunk += 8) {
            int n = chunk * 8 + brow8;
            const unsigned short* g = Bb + (size_t)n * lda + k0 + bc16 * 8;
            __builtin_amdgcn_global_load_lds(
                (const __attribute__((address_space(1))) unsigned int*)g,
                (__attribute__((address_space(3))) unsigned int*)&Bs[chunk * 512], 16, 0, 0);
        }
        // A DMA: 16 chunks (128 rows)
#pragma unroll
        for (int j = 0; j < 2; ++j) {
            int chunk = wid * 2 + j;
            int row = chunk * 8 + brow8;
            const unsigned short* g = Ab + (size_t)row * lda + k0 + bc16 * 8;
            __builtin_amdgcn_global_load_lds(
                (const __attribute__((address_space(1))) unsigned int*)g,
                (__attribute__((address_space(3))) unsigned int*)&As[chunk * 512], 16, 0, 0);
        }
        __syncthreads();
#pragma unroll
        for (int ks = 0; ks < 2; ++ks) {
            f16x8 af[2];
#pragma unroll
            for (int mf = 0; mf < 2; ++mf) {
                int ra = wm * 32 + mf * 16 + l15;
                int c16 = (ks * 4 + l4) ^ (ra & 7);
                af[mf] = *(const f16x8*)&As[ra * 64 + c16 * 8];
            }
#pragma unroll
            for (int nf = 0; nf < 5; ++nf) {
                int rb = wn * 80 + nf * 16 + l15;
                int c16 = (ks * 4 + l4) ^ (rb & 7);
                f16x8 bg = *(const f16x8*)&Bs[rb * 64 + c16 * 8];
#pragma unroll
                for (int mf = 0; mf < 2; ++mf)
                    acc[mf][nf] = __builtin_amdgcn_mfma_f32_16x16x32_f16(af[mf], bg, acc[mf][nf], 0, 0, 0);
            }
        }
        __syncthreads();
    }

    // ---- per-column stats ----
#pragma unroll
    for (int nf = 0; nf < 5; ++nf) {
        int col = n0 + wn * 80 + nf * 16 + l15;
        float s = 0.f, ss = 0.f;
#pragma unroll
        for (int mf = 0; mf < 2; ++mf) {
#pragma unroll
            for (int i = 0; i < 4; ++i) {
                float vr = h2f(f2h(acc[mf][nf][i]));
                s += vr;
                ss += vr * vr;
            }
        }
        s += __shfl_xor(s, 16); s += __shfl_xor(s, 32);
        ss += __shfl_xor(ss, 16); ss += __shfl_xor(ss, 32);
        if (lane < 16) {
            atomicAdd(&stats[col], s);
            atomicAdd(&stats[statN + col], ss);
        }
    }

    // ---- LDS-transpose epilogue: 4 quarter-passes of 32 rows ----
    unsigned short* T = smem;  // 32 x TLDB
#pragma unroll
    for (int q = 0; q < 4; ++q) {
        __syncthreads();
        if (wm == q) {
#pragma unroll
            for (int nf = 0; nf < 5; ++nf) {
                int col = wn * 80 + nf * 16 + l15;
#pragma unroll
                for (int mf = 0; mf < 2; ++mf) {
                    int r = mf * 16 + (l4 << 2);
#pragma unroll
                    for (int i = 0; i < 4; ++i)
                        T[(r + i) * TLDB + col] = f2h(acc[mf][nf][i]);
                }
            }
        }
        __syncthreads();
        int rowbase = m0 + q * 32;
        for (int cid = tid; cid < 32 * 20; cid += 512) {
            int r = cid / 20, c16 = cid % 20;
            uint4v v = *(const uint4v*)&T[r * TLDB + c16 * 8];
            *(uint4v*)&C[(size_t)(rowbase + r) * ldc + n0 + c16 * 8] = v;
        }
    }
}

// ---------------- BN scale/shift from stats (f32 + f16 copies) ----------------
__global__ void k_bnprep(const float* __restrict__ stats, int statN, int realN,
                         const float* __restrict__ g, const float* __restrict__ b,
                         float* __restrict__ sc, float* __restrict__ sh,
                         unsigned short* __restrict__ scH, unsigned short* __restrict__ shH) {
    int n = blockIdx.x * 256 + threadIdx.x;
    if (n >= statN) return;
    float scv = 0.f, shv = 0.f;
    if (n < realN) {
        float mu = stats[n] * (1.f / NN);
        float var = stats[statN + n] * (1.f / NN) - mu * mu;
        var = fmaxf(var, 0.f);
        float rs = rsqrtf(var + BN_EPS);
        scv = g[n] * rs;
        shv = b[n] - mu * scv;
    }
    sc[n] = scv;
    sh[n] = shv;
    scH[n] = f2h(scv);
    shH[n] = f2h(shv);
}

// ---------------- final output ----------------
__global__ void k_out(const unsigned short* __restrict__ u2, const float* __restrict__ sc,
                      const float* __restrict__ sh, float* __restrict__ out) {
    unsigned int idx = blockIdx.x * 256u + threadIdx.x;
    if (idx >= (unsigned int)NN * DD) return;
    unsigned int n = idx / DD, d = idx % DD;
    out[idx] = sc[d] * h2f(u2[(size_t)n * DP + d]) + sh[d];
}

extern "C" void kernel_launch(void* const* d_in, const int* in_sizes, int n_in,
                              void* d_out, int out_size, void* d_ws, size_t ws_size,
                              hipStream_t stream) {
    const int* x = (const int*)d_in[0];
    const int* ei = (const int*)d_in[1];
    const int* ea = (const int*)d_in[2];
    const float* xe1 = (const float*)d_in[3];
    const float* xe2 = (const float*)d_in[4];
    const float* ee1 = (const float*)d_in[5];
    const float* ee2 = (const float*)d_in[6];
    const float* W1 = (const float*)d_in[7];
    const float* bn1g = (const float*)d_in[9];
    const float* bn1b = (const float*)d_in[10];
    const float* W2 = (const float*)d_in[11];
    const float* bng = (const float*)d_in[13];
    const float* bnb = (const float*)d_in[14];
    float* out = (float*)d_out;

    char* ws = (char*)d_ws;
    size_t off = 0;
    auto alloc = [&](size_t bytes) -> void* {
        void* p = ws + off;
        off += (bytes + 255) & ~(size_t)255;
        return p;
    };
    unsigned short* hbuf = (unsigned short*)alloc((size_t)NN * DP * 2);   // h0 / u2
    unsigned short* agg  = (unsigned short*)alloc((size_t)NN * DP * 2);
    unsigned short* u1   = (unsigned short*)alloc((size_t)NN * D2P * 2);
    unsigned short* W1t  = (unsigned short*)alloc((size_t)NL * D2P * DP * 2);
    unsigned short* W2t  = (unsigned short*)alloc((size_t)NL * DP * D2P * 2);
    unsigned short* eec  = (unsigned short*)alloc((size_t)NL * 15 * DP * 2);
    int* row_ptr = (int*)alloc((size_t)(NN + 1) * 4);
    int* cursor  = (int*)alloc((size_t)NN * 4);
    int* counts  = (int*)alloc((size_t)NN * 4);
    int* srcs    = (int*)alloc((size_t)NE * 4);
    int* combos  = (int*)alloc((size_t)NE * 4);
    int* partial  = (int*)alloc(512 * 4);
    int* partial2 = (int*)alloc(512 * 4);
    float* stats1 = (float*)alloc(2 * D2P * 4);
    float* stats2 = (float*)alloc(2 * DP * 4);
    float* sc1 = (float*)alloc(D2P * 4);
    float* sh1 = (float*)alloc(D2P * 4);
    float* sc2 = (float*)alloc(DP * 4);
    float* sh2 = (float*)alloc(DP * 4);
    float* sc0 = (float*)alloc(DP * 4);
    float* sh0 = (float*)alloc(DP * 4);
    unsigned short* scH1 = (unsigned short*)alloc(D2P * 2);
    unsigned short* shH1 = (unsigned short*)alloc(D2P * 2);
    unsigned short* scH2 = (unsigned short*)alloc(DP * 2);
    unsigned short* shH2 = (unsigned short*)alloc(DP * 2);

    // prep
    k_w1t<<<NL * D2P * DP / 256, 256, 0, stream>>>(W1, W1t);
    k_w2t<<<NL * DP * D2P / 256, 256, 0, stream>>>(W2, W2t);
    k_eec<<<(NL * 15 * DP + 255) / 256, 256, 0, stream>>>(ee1, ee2, eec);
    k_h0<<<NN * DP / 256, 256, 0, stream>>>(x, xe1, xe2, hbuf);
    k_ident<<<2, 256, 0, stream>>>(sc0, sh0);

    // CSR
    hipMemsetAsync(counts, 0, (size_t)NN * 4, stream);
    k_count<<<NE / 256, 256, 0, stream>>>(ei, counts);
    k_scan1<<<NN / 256, 256, 0, stream>>>(counts, partial);
    k_scan2<<<1, 512, 0, stream>>>(partial, partial2);
    k_scan3<<<NN / 256, 256, 0, stream>>>(counts, partial2, row_ptr, cursor);
    k_fill<<<NE / 256, 256, 0, stream>>>(ei, ea, cursor, srcs, combos);

    const unsigned short* hcur = hbuf;
    const float* scIn = sc0;
    const float* shIn = sh0;
    int reluIn = 0;
    for (int l = 0; l < NL; ++l) {
        k_gather<<<NN * 40 / 256, 256, 0, stream>>>(hcur, scIn, shIn, reluIn, row_ptr, srcs,
                                                    combos, eec + (size_t)l * 15 * DP, agg);
        hipMemsetAsync(stats1, 0, 2 * D2P * 4, stream);
        if (l & 1) {
            dim3 g1(D2P / 320, NN / 128);
            k_gemm_dma<<<g1, 512, 0, stream>>>(agg, DP, DP / 64,
                                               W1t + (size_t)l * D2P * DP, u1, D2P, stats1, D2P);
        } else {
            dim3 g1(D2P / 160, NN / 128);
            k_gemm_b160<<<g1, 512, 0, stream>>>(agg, DP, DP / 64,
                                                W1t + (size_t)l * D2P * DP, u1, D2P, stats1, D2P);
        }
        k_bnprep<<<(D2P + 255) / 256, 256, 0, stream>>>(stats1, D2P, D2, bn1g + (size_t)l * D2,
                                                        bn1b + (size_t)l * D2, sc1, sh1, scH1, shH1);
        hipMemsetAsync(stats2, 0, 2 * DP * 4, stream);
        dim3 g2(DP / 320, NN / 128);
        k_gemm_r4<<<g2, 512, 0, stream>>>(u1, D2P, D2P / 64, scH1, shH1,
                                          W2t + (size_t)l * DP * D2P, hbuf, DP, stats2, DP);
        k_bnprep<<<(DP + 255) / 256, 256, 0, stream>>>(stats2, DP, DD, bng + (size_t)l * DD,
                                                       bnb + (size_t)l * DD, sc2, sh2, scH2, shH2);
        hcur = hbuf;
        scIn = sc2;
        shIn = sh2;
        reluIn = 1;
    }
    k_out<<<(unsigned int)NN * DD / 256, 256, 0, stream>>>(hbuf, sc2, sh2, out);
}

// Round 18
// 1836.181 us; speedup vs baseline: 1.2386x; 1.0316x over previous
//
#include <hip/hip_runtime.h>
#include <hip/hip_bf16.h>
#include <stdint.h>

#define NN 131072
#define NE 262144
#define DD 300
#define DP 320
#define D2 600
#define D2P 640
#define NL 5
#define BN_EPS 1e-5f

typedef __attribute__((ext_vector_type(8))) _Float16 f16x8;
typedef __attribute__((ext_vector_type(4))) float f32x4;
typedef __attribute__((ext_vector_type(4))) unsigned int uint4v;

static __device__ __forceinline__ float h2f(unsigned short u) {
    union { unsigned short u; _Float16 h; } c; c.u = u; return (float)c.h;
}
static __device__ __forceinline__ unsigned short f2h(float f) {
    union { unsigned short u; _Float16 h; } c; c.h = (_Float16)f; return c.u;
}

// ---------------- prep kernels ----------------

__global__ void k_w1t(const float* __restrict__ W1, unsigned short* __restrict__ W1t) {
    int idx = blockIdx.x * 256 + threadIdx.x;
    if (idx >= NL * D2P * DP) return;
    int l = idx / (D2P * DP);
    int r = idx % (D2P * DP);
    int n = r / DP, k = r % DP;
    float v = (n < D2 && k < DD) ? W1[(size_t)(l * DD + k) * D2 + n] : 0.f;
    W1t[idx] = f2h(v);
}

__global__ void k_w2t(const float* __restrict__ W2, unsigned short* __restrict__ W2t) {
    int idx = blockIdx.x * 256 + threadIdx.x;
    if (idx >= NL * DP * D2P) return;
    int l = idx / (DP * D2P);
    int r = idx % (DP * D2P);
    int n = r / D2P, k = r % D2P;
    float v = (n < DD && k < D2) ? W2[(size_t)(l * D2 + k) * DD + n] : 0.f;
    W2t[idx] = f2h(v);
}

__global__ void k_eec(const float* __restrict__ ee1, const float* __restrict__ ee2,
                      unsigned short* __restrict__ eec) {
    int idx = blockIdx.x * 256 + threadIdx.x;
    if (idx >= NL * 15 * DP) return;
    int l = idx / (15 * DP);
    int r = idx % (15 * DP);
    int cb = r / DP, c = r % DP;
    int b = cb / 3, d = cb % 3;
    float v = 0.f;
    if (c < DD) v = ee1[(size_t)(l * 5 + b) * DD + c] + ee2[(size_t)(l * 3 + d) * DD + c];
    eec[idx] = f2h(v);
}

__global__ void k_h0(const int* __restrict__ x, const float* __restrict__ xe1,
                     const float* __restrict__ xe2, unsigned short* __restrict__ h) {
    unsigned int idx = blockIdx.x * 256u + threadIdx.x;
    if (idx >= (unsigned int)NN * DP) return;
    unsigned int n = idx / DP, c = idx % DP;
    float v = 0.f;
    if (c < DD) v = xe1[(size_t)x[2 * n] * DD + c] + xe2[(size_t)x[2 * n + 1] * DD + c];
    h[idx] = f2h(v);
}

__global__ void k_ident(float* __restrict__ sc, float* __restrict__ sh) {
    int t = blockIdx.x * 256 + threadIdx.x;
    if (t < DP) { sc[t] = 1.f; sh[t] = 0.f; }
}

// ---------------- CSR build ----------------

__global__ void k_count(const int* __restrict__ ei, int* __restrict__ counts) {
    int e = blockIdx.x * 256 + threadIdx.x;
    if (e < NE) atomicAdd(&counts[ei[NE + e]], 1);
}

__global__ void k_scan1(const int* __restrict__ counts, int* __restrict__ partial) {
    __shared__ int sm[256];
    int t = threadIdx.x;
    sm[t] = counts[blockIdx.x * 256 + t];
    __syncthreads();
    for (int o = 128; o > 0; o >>= 1) {
        if (t < o) sm[t] += sm[t + o];
        __syncthreads();
    }
    if (t == 0) partial[blockIdx.x] = sm[0];
}

__global__ void k_scan2(const int* __restrict__ partial, int* __restrict__ partial2) {
    __shared__ int sm[512];
    int t = threadIdx.x;
    int v = partial[t];
    sm[t] = v;
    __syncthreads();
    for (int o = 1; o < 512; o <<= 1) {
        int add = (t >= o) ? sm[t - o] : 0;
        __syncthreads();
        sm[t] += add;
        __syncthreads();
    }
    partial2[t] = sm[t] - v;  // exclusive
}

__global__ void k_scan3(const int* __restrict__ counts, const int* __restrict__ partial2,
                        int* __restrict__ row_ptr, int* __restrict__ cursor) {
    __shared__ int sm[256];
    int t = threadIdx.x;
    int i = blockIdx.x * 256 + t;
    int v = counts[i];
    sm[t] = v;
    __syncthreads();
    for (int o = 1; o < 256; o <<= 1) {
        int add = (t >= o) ? sm[t - o] : 0;
        __syncthreads();
        sm[t] += add;
        __syncthreads();
    }
    int excl = partial2[blockIdx.x] + sm[t] - v;
    row_ptr[i] = excl;
    cursor[i] = excl;
    if (i == NN - 1) row_ptr[NN] = excl + v;
}

__global__ void k_fill(const int* __restrict__ ei, const int* __restrict__ ea,
                       int* __restrict__ cursor, int* __restrict__ srcs,
                       int* __restrict__ combos) {
    int e = blockIdx.x * 256 + threadIdx.x;
    if (e >= NE) return;
    int d = ei[NE + e];
    int pos = atomicAdd(&cursor[d], 1);
    srcs[pos] = ei[e];
    combos[pos] = ea[2 * e] * 3 + ea[2 * e + 1];
}

// ---------------- aggregation (pull, CSR) ----------------
__global__ void k_gather(const unsigned short* __restrict__ h, const float* __restrict__ sc,
                         const float* __restrict__ sh, int relu,
                         const int* __restrict__ row_ptr, const int* __restrict__ srcs,
                         const int* __restrict__ combos, const unsigned short* __restrict__ eec,
                         unsigned short* __restrict__ agg) {
    unsigned int idx = blockIdx.x * 256u + threadIdx.x;  // N*40 chunks of 8 cols
    if (idx >= (unsigned int)NN * 40) return;
    unsigned int m = idx / 40;
    unsigned int j = idx % 40;
    int c0 = j * 8;
    float a[8] = {0, 0, 0, 0, 0, 0, 0, 0};
    float scv[8], shv[8];
#pragma unroll
    for (int i = 0; i < 8; i++) { scv[i] = sc[c0 + i]; shv[i] = sh[c0 + i]; }
    int e0 = row_ptr[m], e1 = row_ptr[m + 1];
    for (int e = e0; e < e1; ++e) {
        int s = srcs[e], cb = combos[e];
        uint4v hv = *(const uint4v*)(h + (size_t)s * DP + c0);
        uint4v ev = *(const uint4v*)(eec + (size_t)cb * DP + c0);
        const unsigned short* hp = (const unsigned short*)&hv;
        const unsigned short* ep = (const unsigned short*)&ev;
#pragma unroll
        for (int i = 0; i < 8; i++) {
            float f = scv[i] * h2f(hp[i]) + shv[i];
            if (relu) f = fmaxf(f, 0.f);
            a[i] += f + h2f(ep[i]);
        }
    }
    unsigned short o[8];
#pragma unroll
    for (int i = 0; i < 8; i++) o[i] = f2h(a[i]);
    *(uint4v*)(agg + (size_t)m * DP + c0) = *(const uint4v*)o;
}

// ---------------- k_gemm_r4: round-4 GEMM with reg-staged A + affine fold (142 us) ----------------
#define TLD 328
__launch_bounds__(512, 2)
__global__ void k_gemm_r4(const unsigned short* __restrict__ A, int lda, int kIters,
                          const unsigned short* __restrict__ scH,
                          const unsigned short* __restrict__ shH,
                          const unsigned short* __restrict__ B,
                          unsigned short* __restrict__ C, int ldc,
                          float* __restrict__ stats, int statN) {
    __shared__ unsigned short smem[128 * 64 + 320 * 64];
    unsigned short* As = smem;
    unsigned short* Bs = smem + 128 * 64;
    int tid = threadIdx.x;
    int lane = tid & 63, wid = tid >> 6;
    int wm = wid >> 2, wn = wid & 3;
    int m0 = blockIdx.y * 128;
    int n0 = blockIdx.x * 320;
    const unsigned short* Bb = B + (size_t)n0 * lda;

    int srow = tid >> 2;
    int sc16 = tid & 3;
    int swz = srow & 7;
    const unsigned short* aRow = A + (size_t)(m0 + srow) * lda;
    int brow8 = lane >> 3;
    int bc16 = (lane & 7) ^ brow8;

    f32x4 acc[4][5] = {};

    for (int kt = 0; kt < kIters; ++kt) {
        int k0 = kt * 64;
#pragma unroll
        for (int j = 0; j < 5; ++j) {
            int chunk = wid * 5 + j;
            int n = chunk * 8 + brow8;
            const unsigned short* g = Bb + (size_t)n * lda + k0 + bc16 * 8;
            __builtin_amdgcn_global_load_lds(
                (const __attribute__((address_space(1))) unsigned int*)g,
                (__attribute__((address_space(3))) unsigned int*)&Bs[chunk * 512], 16, 0, 0);
        }
        uint4v v0 = *(const uint4v*)(aRow + k0 + sc16 * 8);
        uint4v v1 = *(const uint4v*)(aRow + k0 + (sc16 + 4) * 8);
        if (scH) {
            f16x8 a0 = *(f16x8*)&v0, a1 = *(f16x8*)&v1;
            f16x8 s0 = *(const f16x8*)&scH[k0 + sc16 * 8];
            f16x8 h0 = *(const f16x8*)&shH[k0 + sc16 * 8];
            f16x8 s1 = *(const f16x8*)&scH[k0 + (sc16 + 4) * 8];
            f16x8 h1 = *(const f16x8*)&shH[k0 + (sc16 + 4) * 8];
#pragma unroll
            for (int i = 0; i < 8; i++) {
                _Float16 t0 = a0[i] * s0[i] + h0[i];
                _Float16 t1 = a1[i] * s1[i] + h1[i];
                a0[i] = t0 > (_Float16)0 ? t0 : (_Float16)0;
                a1[i] = t1 > (_Float16)0 ? t1 : (_Float16)0;
            }
            v0 = *(uint4v*)&a0;
            v1 = *(uint4v*)&a1;
        }
        *(uint4v*)&As[srow * 64 + ((sc16 ^ swz) * 8)] = v0;
        *(uint4v*)&As[srow * 64 + (((sc16 + 4) ^ swz) * 8)] = v1;
        __syncthreads();
#pragma unroll
        for (int ks = 0; ks < 2; ++ks) {
            f16x8 af[4];
#pragma unroll
            for (int mf = 0; mf < 4; ++mf) {
                int ra = wm * 64 + mf * 16 + (lane & 15);
                int c16 = (ks * 4 + (lane >> 4)) ^ (ra & 7);
                af[mf] = *(const f16x8*)&As[ra * 64 + c16 * 8];
            }
#pragma unroll
            for (int nf = 0; nf < 5; ++nf) {
                int rb = wn * 80 + nf * 16 + (lane & 15);
                int c16 = (ks * 4 + (lane >> 4)) ^ (rb & 7);
                f16x8 bg = *(const f16x8*)&Bs[rb * 64 + c16 * 8];
#pragma unroll
                for (int mf = 0; mf < 4; ++mf)
                    acc[mf][nf] = __builtin_amdgcn_mfma_f32_16x16x32_f16(af[mf], bg, acc[mf][nf], 0, 0, 0);
            }
        }
        __syncthreads();
    }

#pragma unroll
    for (int nf = 0; nf < 5; ++nf) {
        int col = n0 + wn * 80 + nf * 16 + (lane & 15);
        float s = 0.f, ss = 0.f;
#pragma unroll
        for (int mf = 0; mf < 4; ++mf) {
#pragma unroll
            for (int i = 0; i < 4; ++i) {
                float vr = h2f(f2h(acc[mf][nf][i]));
                s += vr;
                ss += vr * vr;
            }
        }
        s += __shfl_xor(s, 16); s += __shfl_xor(s, 32);
        ss += __shfl_xor(ss, 16); ss += __shfl_xor(ss, 32);
        if (lane < 16) {
            atomicAdd(&stats[col], s);
            atomicAdd(&stats[statN + col], ss);
        }
    }

    unsigned short* T = smem;
#pragma unroll
    for (int half = 0; half < 2; ++half) {
        __syncthreads();
        if (wm == half) {
#pragma unroll
            for (int nf = 0; nf < 5; ++nf) {
                int col = wn * 80 + nf * 16 + (lane & 15);
#pragma unroll
                for (int mf = 0; mf < 4; ++mf) {
                    int r = mf * 16 + ((lane >> 4) << 2);
#pragma unroll
                    for (int i = 0; i < 4; ++i)
                        T[(r + i) * TLD + col] = f2h(acc[mf][nf][i]);
                }
            }
        }
        __syncthreads();
        int rowbase = m0 + half * 64;
#pragma unroll
        for (int p = 0; p < 5; ++p) {
            int cid = p * 512 + tid;
            int r = cid / 40, c16 = cid % 40;
            uint4v v = *(const uint4v*)&T[r * TLD + c16 * 8];
            *(uint4v*)&C[(size_t)(rowbase + r) * ldc + n0 + c16 * 8] = v;
        }
    }
}

// ---------------- k_gemm_dma: r4 structure, A via global_load_lds (142 us, 4x fewer conflicts) ----------------
__launch_bounds__(512, 2)
__global__ void k_gemm_dma(const unsigned short* __restrict__ A, int lda, int kIters,
                           const unsigned short* __restrict__ B,
                           unsigned short* __restrict__ C, int ldc,
                           float* __restrict__ stats, int statN) {
    __shared__ unsigned short smem[128 * 64 + 320 * 64];
    unsigned short* As = smem;
    unsigned short* Bs = smem + 128 * 64;
    int tid = threadIdx.x;
    int lane = tid & 63, wid = tid >> 6;
    int wm = wid >> 2, wn = wid & 3;
    int m0 = blockIdx.y * 128;
    int n0 = blockIdx.x * 320;
    const unsigned short* Bb = B + (size_t)n0 * lda;
    const unsigned short* Ab = A + (size_t)m0 * lda;

    int brow8 = lane >> 3;
    int bc16 = (lane & 7) ^ brow8;

    f32x4 acc[4][5] = {};

    for (int kt = 0; kt < kIters; ++kt) {
        int k0 = kt * 64;
#pragma unroll
        for (int j = 0; j < 5; ++j) {
            int chunk = wid * 5 + j;
            int n = chunk * 8 + brow8;
            const unsigned short* g = Bb + (size_t)n * lda + k0 + bc16 * 8;
            __builtin_amdgcn_global_load_lds(
                (const __attribute__((address_space(1))) unsigned int*)g,
                (__attribute__((address_space(3))) unsigned int*)&Bs[chunk * 512], 16, 0, 0);
        }
#pragma unroll
        for (int j = 0; j < 2; ++j) {
            int chunk = wid * 2 + j;
            int row = chunk * 8 + brow8;
            const unsigned short* g = Ab + (size_t)row * lda + k0 + bc16 * 8;
            __builtin_amdgcn_global_load_lds(
                (const __attribute__((address_space(1))) unsigned int*)g,
                (__attribute__((address_space(3))) unsigned int*)&As[chunk * 512], 16, 0, 0);
        }
        __syncthreads();
#pragma unroll
        for (int ks = 0; ks < 2; ++ks) {
            f16x8 af[4];
#pragma unroll
            for (int mf = 0; mf < 4; ++mf) {
                int ra = wm * 64 + mf * 16 + (lane & 15);
                int c16 = (ks * 4 + (lane >> 4)) ^ (ra & 7);
                af[mf] = *(const f16x8*)&As[ra * 64 + c16 * 8];
            }
#pragma unroll
            for (int nf = 0; nf < 5; ++nf) {
                int rb = wn * 80 + nf * 16 + (lane & 15);
                int c16 = (ks * 4 + (lane >> 4)) ^ (rb & 7);
                f16x8 bg = *(const f16x8*)&Bs[rb * 64 + c16 * 8];
#pragma unroll
                for (int mf = 0; mf < 4; ++mf)
                    acc[mf][nf] = __builtin_amdgcn_mfma_f32_16x16x32_f16(af[mf], bg, acc[mf][nf], 0, 0, 0);
            }
        }
        __syncthreads();
    }

#pragma unroll
    for (int nf = 0; nf < 5; ++nf) {
        int col = n0 + wn * 80 + nf * 16 + (lane & 15);
        float s = 0.f, ss = 0.f;
#pragma unroll
        for (int mf = 0; mf < 4; ++mf) {
#pragma unroll
            for (int i = 0; i < 4; ++i) {
                float vr = h2f(f2h(acc[mf][nf][i]));
                s += vr;
                ss += vr * vr;
            }
        }
        s += __shfl_xor(s, 16); s += __shfl_xor(s, 32);
        ss += __shfl_xor(ss, 16); ss += __shfl_xor(ss, 32);
        if (lane < 16) {
            atomicAdd(&stats[col], s);
            atomicAdd(&stats[statN + col], ss);
        }
    }

    unsigned short* T = smem;
#pragma unroll
    for (int half = 0; half < 2; ++half) {
        __syncthreads();
        if (wm == half) {
#pragma unroll
            for (int nf = 0; nf < 5; ++nf) {
                int col = wn * 80 + nf * 16 + (lane & 15);
#pragma unroll
                for (int mf = 0; mf < 4; ++mf) {
                    int r = mf * 16 + ((lane >> 4) << 2);
#pragma unroll
                    for (int i = 0; i < 4; ++i)
                        T[(r + i) * TLD + col] = f2h(acc[mf][nf][i]);
                }
            }
        }
        __syncthreads();
        int rowbase = m0 + half * 64;
#pragma unroll
        for (int p = 0; p < 5; ++p) {
            int cid = p * 512 + tid;
            int r = cid / 40, c16 = cid % 40;
            uint4v v = *(const uint4v*)&T[r * TLD + c16 * 8];
            *(uint4v*)&C[(size_t)(rowbase + r) * ldc + n0 + c16 * 8] = v;
        }
    }
}

// ---------------- BN scale/shift from stats (f32 + f16 copies) ----------------
__global__ void k_bnprep(const float* __restrict__ stats, int statN, int realN,
                         const float* __restrict__ g, const float* __restrict__ b,
                         float* __restrict__ sc, float* __restrict__ sh,
                         unsigned short* __restrict__ scH, unsigned short* __restrict__ shH) {
    int n = blockIdx.x * 256 + threadIdx.x;
    if (n >= statN) return;
    float scv = 0.f, shv = 0.f;
    if (n < realN) {
        float mu = stats[n] * (1.f / NN);
        float var = stats[statN + n] * (1.f / NN) - mu * mu;
        var = fmaxf(var, 0.f);
        float rs = rsqrtf(var + BN_EPS);
        scv = g[n] * rs;
        shv = b[n] - mu * scv;
    }
    sc[n] = scv;
    sh[n] = shv;
    scH[n] = f2h(scv);
    shH[n] = f2h(shv);
}

// ---------------- final output ----------------
__global__ void k_out(const unsigned short* __restrict__ u2, const float* __restrict__ sc,
                      const float* __restrict__ sh, float* __restrict__ out) {
    unsigned int idx = blockIdx.x * 256u + threadIdx.x;
    if (idx >= (unsigned int)NN * DD) return;
    unsigned int n = idx / DD, d = idx % DD;
    out[idx] = sc[d] * h2f(u2[(size_t)n * DP + d]) + sh[d];
}

extern "C" void kernel_launch(void* const* d_in, const int* in_sizes, int n_in,
                              void* d_out, int out_size, void* d_ws, size_t ws_size,
                              hipStream_t stream) {
    const int* x = (const int*)d_in[0];
    const int* ei = (const int*)d_in[1];
    const int* ea = (const int*)d_in[2];
    const float* xe1 = (const float*)d_in[3];
    const float* xe2 = (const float*)d_in[4];
    const float* ee1 = (const float*)d_in[5];
    const float* ee2 = (const float*)d_in[6];
    const float* W1 = (const float*)d_in[7];
    const float* bn1g = (const float*)d_in[9];
    const float* bn1b = (const float*)d_in[10];
    const float* W2 = (const float*)d_in[11];
    const float* bng = (const float*)d_in[13];
    const float* bnb = (const float*)d_in[14];
    float* out = (float*)d_out;

    char* ws = (char*)d_ws;
    size_t off = 0;
    auto alloc = [&](size_t bytes) -> void* {
        void* p = ws + off;
        off += (bytes + 255) & ~(size_t)255;
        return p;
    };
    unsigned short* hbuf = (unsigned short*)alloc((size_t)NN * DP * 2);   // h0 / u2
    unsigned short* agg  = (unsigned short*)alloc((size_t)NN * DP * 2);
    unsigned short* u1   = (unsigned short*)alloc((size_t)NN * D2P * 2);
    unsigned short* W1t  = (unsigned short*)alloc((size_t)NL * D2P * DP * 2);
    unsigned short* W2t  = (unsigned short*)alloc((size_t)NL * DP * D2P * 2);
    unsigned short* eec  = (unsigned short*)alloc((size_t)NL * 15 * DP * 2);
    int* row_ptr = (int*)alloc((size_t)(NN + 1) * 4);
    int* cursor  = (int*)alloc((size_t)NN * 4);
    int* counts  = (int*)alloc((size_t)NN * 4);
    int* srcs    = (int*)alloc((size_t)NE * 4);
    int* combos  = (int*)alloc((size_t)NE * 4);
    int* partial  = (int*)alloc(512 * 4);
    int* partial2 = (int*)alloc(512 * 4);
    float* stats1 = (float*)alloc(2 * D2P * 4);
    float* stats2 = (float*)alloc(2 * DP * 4);
    float* sc1 = (float*)alloc(D2P * 4);
    float* sh1 = (float*)alloc(D2P * 4);
    float* sc2 = (float*)alloc(DP * 4);
    float* sh2 = (float*)alloc(DP * 4);
    float* sc0 = (float*)alloc(DP * 4);
    float* sh0 = (float*)alloc(DP * 4);
    unsigned short* scH1 = (unsigned short*)alloc(D2P * 2);
    unsigned short* shH1 = (unsigned short*)alloc(D2P * 2);
    unsigned short* scH2 = (unsigned short*)alloc(DP * 2);
    unsigned short* shH2 = (unsigned short*)alloc(DP * 2);

    // prep
    k_w1t<<<NL * D2P * DP / 256, 256, 0, stream>>>(W1, W1t);
    k_w2t<<<NL * DP * D2P / 256, 256, 0, stream>>>(W2, W2t);
    k_eec<<<(NL * 15 * DP + 255) / 256, 256, 0, stream>>>(ee1, ee2, eec);
    k_h0<<<NN * DP / 256, 256, 0, stream>>>(x, xe1, xe2, hbuf);
    k_ident<<<2, 256, 0, stream>>>(sc0, sh0);

    // CSR
    hipMemsetAsync(counts, 0, (size_t)NN * 4, stream);
    k_count<<<NE / 256, 256, 0, stream>>>(ei, counts);
    k_scan1<<<NN / 256, 256, 0, stream>>>(counts, partial);
    k_scan2<<<1, 512, 0, stream>>>(partial, partial2);
    k_scan3<<<NN / 256, 256, 0, stream>>>(counts, partial2, row_ptr, cursor);
    k_fill<<<NE / 256, 256, 0, stream>>>(ei, ea, cursor, srcs, combos);

    const unsigned short* hcur = hbuf;
    const float* scIn = sc0;
    const float* shIn = sh0;
    int reluIn = 0;
    for (int l = 0; l < NL; ++l) {
        k_gather<<<NN * 40 / 256, 256, 0, stream>>>(hcur, scIn, shIn, reluIn, row_ptr, srcs,
                                                    combos, eec + (size_t)l * 15 * DP, agg);
        hipMemsetAsync(stats1, 0, 2 * D2P * 4, stream);
        dim3 g1(D2P / 320, NN / 128);
        k_gemm_dma<<<g1, 512, 0, stream>>>(agg, DP, DP / 64,
                                           W1t + (size_t)l * D2P * DP, u1, D2P, stats1, D2P);
        k_bnprep<<<(D2P + 255) / 256, 256, 0, stream>>>(stats1, D2P, D2, bn1g + (size_t)l * D2,
                                                        bn1b + (size_t)l * D2, sc1, sh1, scH1, shH1);
        hipMemsetAsync(stats2, 0, 2 * DP * 4, stream);
        dim3 g2(DP / 320, NN / 128);
        k_gemm_r4<<<g2, 512, 0, stream>>>(u1, D2P, D2P / 64, scH1, shH1,
                                          W2t + (size_t)l * DP * D2P, hbuf, DP, stats2, DP);
        k_bnprep<<<(DP + 255) / 256, 256, 0, stream>>>(stats2, DP, DD, bng + (size_t)l * DD,
                                                       bnb + (size_t)l * DD, sc2, sh2, scH2, shH2);
        hcur = hbuf;
        scIn = sc2;
        shIn = sh2;
        reluIn = 1;
    }
    k_out<<<(unsigned int)NN * DD / 256, 256, 0, stream>>>(hbuf, sc2, sh2, out);
}

// Round 19
// 1832.718 us; speedup vs baseline: 1.2410x; 1.0019x over previous
//
#include <hip/hip_runtime.h>
#include <hip/hip_bf16.h>
#include <stdint.h>

#define NN 131072
#define NE 262144
#define DD 300
#define DP 320
#define D2 600
#define D2P 640
#define NL 5
#define BN_EPS 1e-5f

typedef __attribute__((ext_vector_type(8))) _Float16 f16x8;
typedef __attribute__((ext_vector_type(4))) float f32x4;
typedef __attribute__((ext_vector_type(4))) unsigned int uint4v;

static __device__ __forceinline__ float h2f(unsigned short u) {
    union { unsigned short u; _Float16 h; } c; c.u = u; return (float)c.h;
}
static __device__ __forceinline__ unsigned short f2h(float f) {
    union { unsigned short u; _Float16 h; } c; c.h = (_Float16)f; return c.u;
}

// ---------------- prep kernels ----------------

__global__ void k_w1t(const float* __restrict__ W1, unsigned short* __restrict__ W1t) {
    int idx = blockIdx.x * 256 + threadIdx.x;
    if (idx >= NL * D2P * DP) return;
    int l = idx / (D2P * DP);
    int r = idx % (D2P * DP);
    int n = r / DP, k = r % DP;
    float v = (n < D2 && k < DD) ? W1[(size_t)(l * DD + k) * D2 + n] : 0.f;
    W1t[idx] = f2h(v);
}

__global__ void k_w2t(const float* __restrict__ W2, unsigned short* __restrict__ W2t) {
    int idx = blockIdx.x * 256 + threadIdx.x;
    if (idx >= NL * DP * D2P) return;
    int l = idx / (DP * D2P);
    int r = idx % (DP * D2P);
    int n = r / D2P, k = r % D2P;
    float v = (n < DD && k < D2) ? W2[(size_t)(l * D2 + k) * DD + n] : 0.f;
    W2t[idx] = f2h(v);
}

__global__ void k_eec(const float* __restrict__ ee1, const float* __restrict__ ee2,
                      unsigned short* __restrict__ eec) {
    int idx = blockIdx.x * 256 + threadIdx.x;
    if (idx >= NL * 15 * DP) return;
    int l = idx / (15 * DP);
    int r = idx % (15 * DP);
    int cb = r / DP, c = r % DP;
    int b = cb / 3, d = cb % 3;
    float v = 0.f;
    if (c < DD) v = ee1[(size_t)(l * 5 + b) * DD + c] + ee2[(size_t)(l * 3 + d) * DD + c];
    eec[idx] = f2h(v);
}

__global__ void k_h0(const int* __restrict__ x, const float* __restrict__ xe1,
                     const float* __restrict__ xe2, unsigned short* __restrict__ h) {
    unsigned int idx = blockIdx.x * 256u + threadIdx.x;
    if (idx >= (unsigned int)NN * DP) return;
    unsigned int n = idx / DP, c = idx % DP;
    float v = 0.f;
    if (c < DD) v = xe1[(size_t)x[2 * n] * DD + c] + xe2[(size_t)x[2 * n + 1] * DD + c];
    h[idx] = f2h(v);
}

__global__ void k_ident(float* __restrict__ sc, float* __restrict__ sh) {
    int t = blockIdx.x * 256 + threadIdx.x;
    if (t < DP) { sc[t] = 1.f; sh[t] = 0.f; }
}

// ---------------- CSR build ----------------

__global__ void k_count(const int* __restrict__ ei, int* __restrict__ counts) {
    int e = blockIdx.x * 256 + threadIdx.x;
    if (e < NE) atomicAdd(&counts[ei[NE + e]], 1);
}

__global__ void k_scan1(const int* __restrict__ counts, int* __restrict__ partial) {
    __shared__ int sm[256];
    int t = threadIdx.x;
    sm[t] = counts[blockIdx.x * 256 + t];
    __syncthreads();
    for (int o = 128; o > 0; o >>= 1) {
        if (t < o) sm[t] += sm[t + o];
        __syncthreads();
    }
    if (t == 0) partial[blockIdx.x] = sm[0];
}

__global__ void k_scan2(const int* __restrict__ partial, int* __restrict__ partial2) {
    __shared__ int sm[512];
    int t = threadIdx.x;
    int v = partial[t];
    sm[t] = v;
    __syncthreads();
    for (int o = 1; o < 512; o <<= 1) {
        int add = (t >= o) ? sm[t - o] : 0;
        __syncthreads();
        sm[t] += add;
        __syncthreads();
    }
    partial2[t] = sm[t] - v;  // exclusive
}

__global__ void k_scan3(const int* __restrict__ counts, const int* __restrict__ partial2,
                        int* __restrict__ row_ptr, int* __restrict__ cursor) {
    __shared__ int sm[256];
    int t = threadIdx.x;
    int i = blockIdx.x * 256 + t;
    int v = counts[i];
    sm[t] = v;
    __syncthreads();
    for (int o = 1; o < 256; o <<= 1) {
        int add = (t >= o) ? sm[t - o] : 0;
        __syncthreads();
        sm[t] += add;
        __syncthreads();
    }
    int excl = partial2[blockIdx.x] + sm[t] - v;
    row_ptr[i] = excl;
    cursor[i] = excl;
    if (i == NN - 1) row_ptr[NN] = excl + v;
}

__global__ void k_fill(const int* __restrict__ ei, const int* __restrict__ ea,
                       int* __restrict__ cursor, int* __restrict__ srcs,
                       int* __restrict__ combos) {
    int e = blockIdx.x * 256 + threadIdx.x;
    if (e >= NE) return;
    int d = ei[NE + e];
    int pos = atomicAdd(&cursor[d], 1);
    srcs[pos] = ei[e];
    combos[pos] = ea[2 * e] * 3 + ea[2 * e + 1];
}

// ---------------- aggregation (pull, CSR) ----------------
__global__ void k_gather(const unsigned short* __restrict__ h, const float* __restrict__ sc,
                         const float* __restrict__ sh, int relu,
                         const int* __restrict__ row_ptr, const int* __restrict__ srcs,
                         const int* __restrict__ combos, const unsigned short* __restrict__ eec,
                         unsigned short* __restrict__ agg) {
    unsigned int idx = blockIdx.x * 256u + threadIdx.x;  // N*40 chunks of 8 cols
    if (idx >= (unsigned int)NN * 40) return;
    unsigned int m = idx / 40;
    unsigned int j = idx % 40;
    int c0 = j * 8;
    float a[8] = {0, 0, 0, 0, 0, 0, 0, 0};
    float scv[8], shv[8];
#pragma unroll
    for (int i = 0; i < 8; i++) { scv[i] = sc[c0 + i]; shv[i] = sh[c0 + i]; }
    int e0 = row_ptr[m], e1 = row_ptr[m + 1];
    for (int e = e0; e < e1; ++e) {
        int s = srcs[e], cb = combos[e];
        uint4v hv = *(const uint4v*)(h + (size_t)s * DP + c0);
        uint4v ev = *(const uint4v*)(eec + (size_t)cb * DP + c0);
        const unsigned short* hp = (const unsigned short*)&hv;
        const unsigned short* ep = (const unsigned short*)&ev;
#pragma unroll
        for (int i = 0; i < 8; i++) {
            float f = scv[i] * h2f(hp[i]) + shv[i];
            if (relu) f = fmaxf(f, 0.f);
            a[i] += f + h2f(ep[i]);
        }
    }
    unsigned short o[8];
#pragma unroll
    for (int i = 0; i < 8; i++) o[i] = f2h(a[i]);
    *(uint4v*)(agg + (size_t)m * DP + c0) = *(const uint4v*)o;
}

// ---------------- k_gemm_r4: reg-staged A + affine fold (142 us) + T5 setprio ----------------
#define TLD 328
__launch_bounds__(512, 2)
__global__ void k_gemm_r4(const unsigned short* __restrict__ A, int lda, int kIters,
                          const unsigned short* __restrict__ scH,
                          const unsigned short* __restrict__ shH,
                          const unsigned short* __restrict__ B,
                          unsigned short* __restrict__ C, int ldc,
                          float* __restrict__ stats, int statN) {
    __shared__ unsigned short smem[128 * 64 + 320 * 64];
    unsigned short* As = smem;
    unsigned short* Bs = smem + 128 * 64;
    int tid = threadIdx.x;
    int lane = tid & 63, wid = tid >> 6;
    int wm = wid >> 2, wn = wid & 3;
    int m0 = blockIdx.y * 128;
    int n0 = blockIdx.x * 320;
    const unsigned short* Bb = B + (size_t)n0 * lda;

    int srow = tid >> 2;
    int sc16 = tid & 3;
    int swz = srow & 7;
    const unsigned short* aRow = A + (size_t)(m0 + srow) * lda;
    int brow8 = lane >> 3;
    int bc16 = (lane & 7) ^ brow8;

    f32x4 acc[4][5] = {};

    for (int kt = 0; kt < kIters; ++kt) {
        int k0 = kt * 64;
#pragma unroll
        for (int j = 0; j < 5; ++j) {
            int chunk = wid * 5 + j;
            int n = chunk * 8 + brow8;
            const unsigned short* g = Bb + (size_t)n * lda + k0 + bc16 * 8;
            __builtin_amdgcn_global_load_lds(
                (const __attribute__((address_space(1))) unsigned int*)g,
                (__attribute__((address_space(3))) unsigned int*)&Bs[chunk * 512], 16, 0, 0);
        }
        uint4v v0 = *(const uint4v*)(aRow + k0 + sc16 * 8);
        uint4v v1 = *(const uint4v*)(aRow + k0 + (sc16 + 4) * 8);
        if (scH) {
            f16x8 a0 = *(f16x8*)&v0, a1 = *(f16x8*)&v1;
            f16x8 s0 = *(const f16x8*)&scH[k0 + sc16 * 8];
            f16x8 h0 = *(const f16x8*)&shH[k0 + sc16 * 8];
            f16x8 s1 = *(const f16x8*)&scH[k0 + (sc16 + 4) * 8];
            f16x8 h1 = *(const f16x8*)&shH[k0 + (sc16 + 4) * 8];
#pragma unroll
            for (int i = 0; i < 8; i++) {
                _Float16 t0 = a0[i] * s0[i] + h0[i];
                _Float16 t1 = a1[i] * s1[i] + h1[i];
                a0[i] = t0 > (_Float16)0 ? t0 : (_Float16)0;
                a1[i] = t1 > (_Float16)0 ? t1 : (_Float16)0;
            }
            v0 = *(uint4v*)&a0;
            v1 = *(uint4v*)&a1;
        }
        *(uint4v*)&As[srow * 64 + ((sc16 ^ swz) * 8)] = v0;
        *(uint4v*)&As[srow * 64 + (((sc16 + 4) ^ swz) * 8)] = v1;
        __syncthreads();
        // T5: favor compute waves over the other resident block's staging waves
        __builtin_amdgcn_s_setprio(1);
#pragma unroll
        for (int ks = 0; ks < 2; ++ks) {
            f16x8 af[4];
#pragma unroll
            for (int mf = 0; mf < 4; ++mf) {
                int ra = wm * 64 + mf * 16 + (lane & 15);
                int c16 = (ks * 4 + (lane >> 4)) ^ (ra & 7);
                af[mf] = *(const f16x8*)&As[ra * 64 + c16 * 8];
            }
#pragma unroll
            for (int nf = 0; nf < 5; ++nf) {
                int rb = wn * 80 + nf * 16 + (lane & 15);
                int c16 = (ks * 4 + (lane >> 4)) ^ (rb & 7);
                f16x8 bg = *(const f16x8*)&Bs[rb * 64 + c16 * 8];
#pragma unroll
                for (int mf = 0; mf < 4; ++mf)
                    acc[mf][nf] = __builtin_amdgcn_mfma_f32_16x16x32_f16(af[mf], bg, acc[mf][nf], 0, 0, 0);
            }
        }
        __builtin_amdgcn_s_setprio(0);
        __syncthreads();
    }

#pragma unroll
    for (int nf = 0; nf < 5; ++nf) {
        int col = n0 + wn * 80 + nf * 16 + (lane & 15);
        float s = 0.f, ss = 0.f;
#pragma unroll
        for (int mf = 0; mf < 4; ++mf) {
#pragma unroll
            for (int i = 0; i < 4; ++i) {
                float vr = h2f(f2h(acc[mf][nf][i]));
                s += vr;
                ss += vr * vr;
            }
        }
        s += __shfl_xor(s, 16); s += __shfl_xor(s, 32);
        ss += __shfl_xor(ss, 16); ss += __shfl_xor(ss, 32);
        if (lane < 16) {
            atomicAdd(&stats[col], s);
            atomicAdd(&stats[statN + col], ss);
        }
    }

    unsigned short* T = smem;
#pragma unroll
    for (int half = 0; half < 2; ++half) {
        __syncthreads();
        if (wm == half) {
#pragma unroll
            for (int nf = 0; nf < 5; ++nf) {
                int col = wn * 80 + nf * 16 + (lane & 15);
#pragma unroll
                for (int mf = 0; mf < 4; ++mf) {
                    int r = mf * 16 + ((lane >> 4) << 2);
#pragma unroll
                    for (int i = 0; i < 4; ++i)
                        T[(r + i) * TLD + col] = f2h(acc[mf][nf][i]);
                }
            }
        }
        __syncthreads();
        int rowbase = m0 + half * 64;
#pragma unroll
        for (int p = 0; p < 5; ++p) {
            int cid = p * 512 + tid;
            int r = cid / 40, c16 = cid % 40;
            uint4v v = *(const uint4v*)&T[r * TLD + c16 * 8];
            *(uint4v*)&C[(size_t)(rowbase + r) * ldc + n0 + c16 * 8] = v;
        }
    }
}

// ---------------- k_gemm_dma: A via global_load_lds (142 us) + T5 setprio ----------------
__launch_bounds__(512, 2)
__global__ void k_gemm_dma(const unsigned short* __restrict__ A, int lda, int kIters,
                           const unsigned short* __restrict__ B,
                           unsigned short* __restrict__ C, int ldc,
                           float* __restrict__ stats, int statN) {
    __shared__ unsigned short smem[128 * 64 + 320 * 64];
    unsigned short* As = smem;
    unsigned short* Bs = smem + 128 * 64;
    int tid = threadIdx.x;
    int lane = tid & 63, wid = tid >> 6;
    int wm = wid >> 2, wn = wid & 3;
    int m0 = blockIdx.y * 128;
    int n0 = blockIdx.x * 320;
    const unsigned short* Bb = B + (size_t)n0 * lda;
    const unsigned short* Ab = A + (size_t)m0 * lda;

    int brow8 = lane >> 3;
    int bc16 = (lane & 7) ^ brow8;

    f32x4 acc[4][5] = {};

    for (int kt = 0; kt < kIters; ++kt) {
        int k0 = kt * 64;
#pragma unroll
        for (int j = 0; j < 5; ++j) {
            int chunk = wid * 5 + j;
            int n = chunk * 8 + brow8;
            const unsigned short* g = Bb + (size_t)n * lda + k0 + bc16 * 8;
            __builtin_amdgcn_global_load_lds(
                (const __attribute__((address_space(1))) unsigned int*)g,
                (__attribute__((address_space(3))) unsigned int*)&Bs[chunk * 512], 16, 0, 0);
        }
#pragma unroll
        for (int j = 0; j < 2; ++j) {
            int chunk = wid * 2 + j;
            int row = chunk * 8 + brow8;
            const unsigned short* g = Ab + (size_t)row * lda + k0 + bc16 * 8;
            __builtin_amdgcn_global_load_lds(
                (const __attribute__((address_space(1))) unsigned int*)g,
                (__attribute__((address_space(3))) unsigned int*)&As[chunk * 512], 16, 0, 0);
        }
        __syncthreads();
        __builtin_amdgcn_s_setprio(1);
#pragma unroll
        for (int ks = 0; ks < 2; ++ks) {
            f16x8 af[4];
#pragma unroll
            for (int mf = 0; mf < 4; ++mf) {
                int ra = wm * 64 + mf * 16 + (lane & 15);
                int c16 = (ks * 4 + (lane >> 4)) ^ (ra & 7);
                af[mf] = *(const f16x8*)&As[ra * 64 + c16 * 8];
            }
#pragma unroll
            for (int nf = 0; nf < 5; ++nf) {
                int rb = wn * 80 + nf * 16 + (lane & 15);
                int c16 = (ks * 4 + (lane >> 4)) ^ (rb & 7);
                f16x8 bg = *(const f16x8*)&Bs[rb * 64 + c16 * 8];
#pragma unroll
                for (int mf = 0; mf < 4; ++mf)
                    acc[mf][nf] = __builtin_amdgcn_mfma_f32_16x16x32_f16(af[mf], bg, acc[mf][nf], 0, 0, 0);
            }
        }
        __builtin_amdgcn_s_setprio(0);
        __syncthreads();
    }

#pragma unroll
    for (int nf = 0; nf < 5; ++nf) {
        int col = n0 + wn * 80 + nf * 16 + (lane & 15);
        float s = 0.f, ss = 0.f;
#pragma unroll
        for (int mf = 0; mf < 4; ++mf) {
#pragma unroll
            for (int i = 0; i < 4; ++i) {
                float vr = h2f(f2h(acc[mf][nf][i]));
                s += vr;
                ss += vr * vr;
            }
        }
        s += __shfl_xor(s, 16); s += __shfl_xor(s, 32);
        ss += __shfl_xor(ss, 16); ss += __shfl_xor(ss, 32);
        if (lane < 16) {
            atomicAdd(&stats[col], s);
            atomicAdd(&stats[statN + col], ss);
        }
    }

    unsigned short* T = smem;
#pragma unroll
    for (int half = 0; half < 2; ++half) {
        __syncthreads();
        if (wm == half) {
#pragma unroll
            for (int nf = 0; nf < 5; ++nf) {
                int col = wn * 80 + nf * 16 + (lane & 15);
#pragma unroll
                for (int mf = 0; mf < 4; ++mf) {
                    int r = mf * 16 + ((lane >> 4) << 2);
#pragma unroll
                    for (int i = 0; i < 4; ++i)
                        T[(r + i) * TLD + col] = f2h(acc[mf][nf][i]);
                }
            }
        }
        __syncthreads();
        int rowbase = m0 + half * 64;
#pragma unroll
        for (int p = 0; p < 5; ++p) {
            int cid = p * 512 + tid;
            int r = cid / 40, c16 = cid % 40;
            uint4v v = *(const uint4v*)&T[r * TLD + c16 * 8];
            *(uint4v*)&C[(size_t)(rowbase + r) * ldc + n0 + c16 * 8] = v;
        }
    }
}

// ---------------- BN scale/shift from stats (f32 + f16 copies) ----------------
__global__ void k_bnprep(const float* __restrict__ stats, int statN, int realN,
                         const float* __restrict__ g, const float* __restrict__ b,
                         float* __restrict__ sc, float* __restrict__ sh,
                         unsigned short* __restrict__ scH, unsigned short* __restrict__ shH) {
    int n = blockIdx.x * 256 + threadIdx.x;
    if (n >= statN) return;
    float scv = 0.f, shv = 0.f;
    if (n < realN) {
        float mu = stats[n] * (1.f / NN);
        float var = stats[statN + n] * (1.f / NN) - mu * mu;
        var = fmaxf(var, 0.f);
        float rs = rsqrtf(var + BN_EPS);
        scv = g[n] * rs;
        shv = b[n] - mu * scv;
    }
    sc[n] = scv;
    sh[n] = shv;
    scH[n] = f2h(scv);
    shH[n] = f2h(shv);
}

// ---------------- final output ----------------
__global__ void k_out(const unsigned short* __restrict__ u2, const float* __restrict__ sc,
                      const float* __restrict__ sh, float* __restrict__ out) {
    unsigned int idx = blockIdx.x * 256u + threadIdx.x;
    if (idx >= (unsigned int)NN * DD) return;
    unsigned int n = idx / DD, d = idx % DD;
    out[idx] = sc[d] * h2f(u2[(size_t)n * DP + d]) + sh[d];
}

extern "C" void kernel_launch(void* const* d_in, const int* in_sizes, int n_in,
                              void* d_out, int out_size, void* d_ws, size_t ws_size,
                              hipStream_t stream) {
    const int* x = (const int*)d_in[0];
    const int* ei = (const int*)d_in[1];
    const int* ea = (const int*)d_in[2];
    const float* xe1 = (const float*)d_in[3];
    const float* xe2 = (const float*)d_in[4];
    const float* ee1 = (const float*)d_in[5];
    const float* ee2 = (const float*)d_in[6];
    const float* W1 = (const float*)d_in[7];
    const float* bn1g = (const float*)d_in[9];
    const float* bn1b = (const float*)d_in[10];
    const float* W2 = (const float*)d_in[11];
    const float* bng = (const float*)d_in[13];
    const float* bnb = (const float*)d_in[14];
    float* out = (float*)d_out;

    char* ws = (char*)d_ws;
    size_t off = 0;
    auto alloc = [&](size_t bytes) -> void* {
        void* p = ws + off;
        off += (bytes + 255) & ~(size_t)255;
        return p;
    };
    unsigned short* hbuf = (unsigned short*)alloc((size_t)NN * DP * 2);   // h0 / u2
    unsigned short* agg  = (unsigned short*)alloc((size_t)NN * DP * 2);
    unsigned short* u1   = (unsigned short*)alloc((size_t)NN * D2P * 2);
    unsigned short* W1t  = (unsigned short*)alloc((size_t)NL * D2P * DP * 2);
    unsigned short* W2t  = (unsigned short*)alloc((size_t)NL * DP * D2P * 2);
    unsigned short* eec  = (unsigned short*)alloc((size_t)NL * 15 * DP * 2);
    int* row_ptr = (int*)alloc((size_t)(NN + 1) * 4);
    int* cursor  = (int*)alloc((size_t)NN * 4);
    int* counts  = (int*)alloc((size_t)NN * 4);
    int* srcs    = (int*)alloc((size_t)NE * 4);
    int* combos  = (int*)alloc((size_t)NE * 4);
    int* partial  = (int*)alloc(512 * 4);
    int* partial2 = (int*)alloc(512 * 4);
    float* stats1 = (float*)alloc(2 * D2P * 4);
    float* stats2 = (float*)alloc(2 * DP * 4);
    float* sc1 = (float*)alloc(D2P * 4);
    float* sh1 = (float*)alloc(D2P * 4);
    float* sc2 = (float*)alloc(DP * 4);
    float* sh2 = (float*)alloc(DP * 4);
    float* sc0 = (float*)alloc(DP * 4);
    float* sh0 = (float*)alloc(DP * 4);
    unsigned short* scH1 = (unsigned short*)alloc(D2P * 2);
    unsigned short* shH1 = (unsigned short*)alloc(D2P * 2);
    unsigned short* scH2 = (unsigned short*)alloc(DP * 2);
    unsigned short* shH2 = (unsigned short*)alloc(DP * 2);

    // prep
    k_w1t<<<NL * D2P * DP / 256, 256, 0, stream>>>(W1, W1t);
    k_w2t<<<NL * DP * D2P / 256, 256, 0, stream>>>(W2, W2t);
    k_eec<<<(NL * 15 * DP + 255) / 256, 256, 0, stream>>>(ee1, ee2, eec);
    k_h0<<<NN * DP / 256, 256, 0, stream>>>(x, xe1, xe2, hbuf);
    k_ident<<<2, 256, 0, stream>>>(sc0, sh0);

    // CSR
    hipMemsetAsync(counts, 0, (size_t)NN * 4, stream);
    k_count<<<NE / 256, 256, 0, stream>>>(ei, counts);
    k_scan1<<<NN / 256, 256, 0, stream>>>(counts, partial);
    k_scan2<<<1, 512, 0, stream>>>(partial, partial2);
    k_scan3<<<NN / 256, 256, 0, stream>>>(counts, partial2, row_ptr, cursor);
    k_fill<<<NE / 256, 256, 0, stream>>>(ei, ea, cursor, srcs, combos);

    const unsigned short* hcur = hbuf;
    const float* scIn = sc0;
    const float* shIn = sh0;
    int reluIn = 0;
    for (int l = 0; l < NL; ++l) {
        k_gather<<<NN * 40 / 256, 256, 0, stream>>>(hcur, scIn, shIn, reluIn, row_ptr, srcs,
                                                    combos, eec + (size_t)l * 15 * DP, agg);
        hipMemsetAsync(stats1, 0, 2 * D2P * 4, stream);
        dim3 g1(D2P / 320, NN / 128);
        k_gemm_dma<<<g1, 512, 0, stream>>>(agg, DP, DP / 64,
                                           W1t + (size_t)l * D2P * DP, u1, D2P, stats1, D2P);
        k_bnprep<<<(D2P + 255) / 256, 256, 0, stream>>>(stats1, D2P, D2, bn1g + (size_t)l * D2,
                                                        bn1b + (size_t)l * D2, sc1, sh1, scH1, shH1);
        hipMemsetAsync(stats2, 0, 2 * DP * 4, stream);
        dim3 g2(DP / 320, NN / 128);
        k_gemm_r4<<<g2, 512, 0, stream>>>(u1, D2P, D2P / 64, scH1, shH1,
                                          W2t + (size_t)l * DP * D2P, hbuf, DP, stats2, DP);
        k_bnprep<<<(DP + 255) / 256, 256, 0, stream>>>(stats2, DP, DD, bng + (size_t)l * DD,
                                                       bnb + (size_t)l * DD, sc2, sh2, scH2, shH2);
        hcur = hbuf;
        scIn = sc2;
        shIn = sh2;
        reluIn = 1;
    }
    k_out<<<(unsigned int)NN * DD / 256, 256, 0, stream>>>(hbuf, sc2, sh2, out);
}

// Round 20
// 1806.030 us; speedup vs baseline: 1.2593x; 1.0148x over previous
//
#include <hip/hip_runtime.h>
#include <hip/hip_bf16.h>
#include <stdint.h>

#define NN 131072
#define NE 262144
#define DD 300
#define DP 320
#define D2 600
#define D2P 640
#define NL 5
#define BN_EPS 1e-5f

typedef __attribute__((ext_vector_type(8))) _Float16 f16x8;
typedef __attribute__((ext_vector_type(4))) float f32x4;
typedef __attribute__((ext_vector_type(4))) unsigned int uint4v;

static __device__ __forceinline__ float h2f(unsigned short u) {
    union { unsigned short u; _Float16 h; } c; c.u = u; return (float)c.h;
}
static __device__ __forceinline__ unsigned short f2h(float f) {
    union { unsigned short u; _Float16 h; } c; c.h = (_Float16)f; return c.u;
}

// ---------------- prep kernels ----------------

__global__ void k_w1t(const float* __restrict__ W1, unsigned short* __restrict__ W1t) {
    int idx = blockIdx.x * 256 + threadIdx.x;
    if (idx >= NL * D2P * DP) return;
    int l = idx / (D2P * DP);
    int r = idx % (D2P * DP);
    int n = r / DP, k = r % DP;
    float v = (n < D2 && k < DD) ? W1[(size_t)(l * DD + k) * D2 + n] : 0.f;
    W1t[idx] = f2h(v);
}

__global__ void k_w2t(const float* __restrict__ W2, unsigned short* __restrict__ W2t) {
    int idx = blockIdx.x * 256 + threadIdx.x;
    if (idx >= NL * DP * D2P) return;
    int l = idx / (DP * D2P);
    int r = idx % (DP * D2P);
    int n = r / D2P, k = r % D2P;
    float v = (n < DD && k < D2) ? W2[(size_t)(l * D2 + k) * DD + n] : 0.f;
    W2t[idx] = f2h(v);
}

__global__ void k_eec(const float* __restrict__ ee1, const float* __restrict__ ee2,
                      unsigned short* __restrict__ eec) {
    int idx = blockIdx.x * 256 + threadIdx.x;
    if (idx >= NL * 15 * DP) return;
    int l = idx / (15 * DP);
    int r = idx % (15 * DP);
    int cb = r / DP, c = r % DP;
    int b = cb / 3, d = cb % 3;
    float v = 0.f;
    if (c < DD) v = ee1[(size_t)(l * 5 + b) * DD + c] + ee2[(size_t)(l * 3 + d) * DD + c];
    eec[idx] = f2h(v);
}

__global__ void k_h0(const int* __restrict__ x, const float* __restrict__ xe1,
                     const float* __restrict__ xe2, unsigned short* __restrict__ h) {
    unsigned int idx = blockIdx.x * 256u + threadIdx.x;
    if (idx >= (unsigned int)NN * DP) return;
    unsigned int n = idx / DP, c = idx % DP;
    float v = 0.f;
    if (c < DD) v = xe1[(size_t)x[2 * n] * DD + c] + xe2[(size_t)x[2 * n + 1] * DD + c];
    h[idx] = f2h(v);
}

// ---------------- CSR build ----------------

__global__ void k_count(const int* __restrict__ ei, int* __restrict__ counts) {
    int e = blockIdx.x * 256 + threadIdx.x;
    if (e < NE) atomicAdd(&counts[ei[NE + e]], 1);
}

__global__ void k_scan1(const int* __restrict__ counts, int* __restrict__ partial) {
    __shared__ int sm[256];
    int t = threadIdx.x;
    sm[t] = counts[blockIdx.x * 256 + t];
    __syncthreads();
    for (int o = 128; o > 0; o >>= 1) {
        if (t < o) sm[t] += sm[t + o];
        __syncthreads();
    }
    if (t == 0) partial[blockIdx.x] = sm[0];
}

__global__ void k_scan2(const int* __restrict__ partial, int* __restrict__ partial2) {
    __shared__ int sm[512];
    int t = threadIdx.x;
    int v = partial[t];
    sm[t] = v;
    __syncthreads();
    for (int o = 1; o < 512; o <<= 1) {
        int add = (t >= o) ? sm[t - o] : 0;
        __syncthreads();
        sm[t] += add;
        __syncthreads();
    }
    partial2[t] = sm[t] - v;  // exclusive
}

__global__ void k_scan3(const int* __restrict__ counts, const int* __restrict__ partial2,
                        int* __restrict__ row_ptr, int* __restrict__ cursor) {
    __shared__ int sm[256];
    int t = threadIdx.x;
    int i = blockIdx.x * 256 + t;
    int v = counts[i];
    sm[t] = v;
    __syncthreads();
    for (int o = 1; o < 256; o <<= 1) {
        int add = (t >= o) ? sm[t - o] : 0;
        __syncthreads();
        sm[t] += add;
        __syncthreads();
    }
    int excl = partial2[blockIdx.x] + sm[t] - v;
    row_ptr[i] = excl;
    cursor[i] = excl;
    if (i == NN - 1) row_ptr[NN] = excl + v;
}

__global__ void k_fill(const int* __restrict__ ei, const int* __restrict__ ea,
                       int* __restrict__ cursor, int* __restrict__ srcs,
                       int* __restrict__ combos) {
    int e = blockIdx.x * 256 + threadIdx.x;
    if (e >= NE) return;
    int d = ei[NE + e];
    int pos = atomicAdd(&cursor[d], 1);
    srcs[pos] = ei[e];
    combos[pos] = ea[2 * e] * 3 + ea[2 * e + 1];
}

// ---------------- aggregation (pull, CSR); block 0 also zeros the stats buffer ----------------
__global__ void k_gather(const unsigned short* __restrict__ h, const float* __restrict__ sc,
                         const float* __restrict__ sh, int relu,
                         const int* __restrict__ row_ptr, const int* __restrict__ srcs,
                         const int* __restrict__ combos, const unsigned short* __restrict__ eec,
                         unsigned short* __restrict__ agg,
                         float* __restrict__ stz, int stzN) {
    if (blockIdx.x == 0) {
        for (int i = threadIdx.x; i < stzN; i += 256) stz[i] = 0.f;
    }
    unsigned int idx = blockIdx.x * 256u + threadIdx.x;  // N*40 chunks of 8 cols
    if (idx >= (unsigned int)NN * 40) return;
    unsigned int m = idx / 40;
    unsigned int j = idx % 40;
    int c0 = j * 8;
    bool aff = (sc != nullptr);
    float a[8] = {0, 0, 0, 0, 0, 0, 0, 0};
    float scv[8], shv[8];
    if (aff) {
#pragma unroll
        for (int i = 0; i < 8; i++) { scv[i] = sc[c0 + i]; shv[i] = sh[c0 + i]; }
    }
    int e0 = row_ptr[m], e1 = row_ptr[m + 1];
    for (int e = e0; e < e1; ++e) {
        int s = srcs[e], cb = combos[e];
        uint4v hv = *(const uint4v*)(h + (size_t)s * DP + c0);
        uint4v ev = *(const uint4v*)(eec + (size_t)cb * DP + c0);
        const unsigned short* hp = (const unsigned short*)&hv;
        const unsigned short* ep = (const unsigned short*)&ev;
#pragma unroll
        for (int i = 0; i < 8; i++) {
            float f = h2f(hp[i]);
            if (aff) {
                f = scv[i] * f + shv[i];
                if (relu) f = fmaxf(f, 0.f);
            }
            a[i] += f + h2f(ep[i]);
        }
    }
    unsigned short o[8];
#pragma unroll
    for (int i = 0; i < 8; i++) o[i] = f2h(a[i]);
    *(uint4v*)(agg + (size_t)m * DP + c0) = *(const uint4v*)o;
}

// ---------------- k_gemm_r4: reg-staged A + affine fold (142 us) ----------------
#define TLD 328
__launch_bounds__(512, 2)
__global__ void k_gemm_r4(const unsigned short* __restrict__ A, int lda, int kIters,
                          const unsigned short* __restrict__ scH,
                          const unsigned short* __restrict__ shH,
                          const unsigned short* __restrict__ B,
                          unsigned short* __restrict__ C, int ldc,
                          float* __restrict__ stats, int statN) {
    __shared__ unsigned short smem[128 * 64 + 320 * 64];
    unsigned short* As = smem;
    unsigned short* Bs = smem + 128 * 64;
    int tid = threadIdx.x;
    int lane = tid & 63, wid = tid >> 6;
    int wm = wid >> 2, wn = wid & 3;
    int m0 = blockIdx.y * 128;
    int n0 = blockIdx.x * 320;
    const unsigned short* Bb = B + (size_t)n0 * lda;

    int srow = tid >> 2;
    int sc16 = tid & 3;
    int swz = srow & 7;
    const unsigned short* aRow = A + (size_t)(m0 + srow) * lda;
    int brow8 = lane >> 3;
    int bc16 = (lane & 7) ^ brow8;

    f32x4 acc[4][5] = {};

    for (int kt = 0; kt < kIters; ++kt) {
        int k0 = kt * 64;
#pragma unroll
        for (int j = 0; j < 5; ++j) {
            int chunk = wid * 5 + j;
            int n = chunk * 8 + brow8;
            const unsigned short* g = Bb + (size_t)n * lda + k0 + bc16 * 8;
            __builtin_amdgcn_global_load_lds(
                (const __attribute__((address_space(1))) unsigned int*)g,
                (__attribute__((address_space(3))) unsigned int*)&Bs[chunk * 512], 16, 0, 0);
        }
        uint4v v0 = *(const uint4v*)(aRow + k0 + sc16 * 8);
        uint4v v1 = *(const uint4v*)(aRow + k0 + (sc16 + 4) * 8);
        if (scH) {
            f16x8 a0 = *(f16x8*)&v0, a1 = *(f16x8*)&v1;
            f16x8 s0 = *(const f16x8*)&scH[k0 + sc16 * 8];
            f16x8 h0 = *(const f16x8*)&shH[k0 + sc16 * 8];
            f16x8 s1 = *(const f16x8*)&scH[k0 + (sc16 + 4) * 8];
            f16x8 h1 = *(const f16x8*)&shH[k0 + (sc16 + 4) * 8];
#pragma unroll
            for (int i = 0; i < 8; i++) {
                _Float16 t0 = a0[i] * s0[i] + h0[i];
                _Float16 t1 = a1[i] * s1[i] + h1[i];
                a0[i] = t0 > (_Float16)0 ? t0 : (_Float16)0;
                a1[i] = t1 > (_Float16)0 ? t1 : (_Float16)0;
            }
            v0 = *(uint4v*)&a0;
            v1 = *(uint4v*)&a1;
        }
        *(uint4v*)&As[srow * 64 + ((sc16 ^ swz) * 8)] = v0;
        *(uint4v*)&As[srow * 64 + (((sc16 + 4) ^ swz) * 8)] = v1;
        __syncthreads();
        __builtin_amdgcn_s_setprio(1);
#pragma unroll
        for (int ks = 0; ks < 2; ++ks) {
            f16x8 af[4];
#pragma unroll
            for (int mf = 0; mf < 4; ++mf) {
                int ra = wm * 64 + mf * 16 + (lane & 15);
                int c16 = (ks * 4 + (lane >> 4)) ^ (ra & 7);
                af[mf] = *(const f16x8*)&As[ra * 64 + c16 * 8];
            }
#pragma unroll
            for (int nf = 0; nf < 5; ++nf) {
                int rb = wn * 80 + nf * 16 + (lane & 15);
                int c16 = (ks * 4 + (lane >> 4)) ^ (rb & 7);
                f16x8 bg = *(const f16x8*)&Bs[rb * 64 + c16 * 8];
#pragma unroll
                for (int mf = 0; mf < 4; ++mf)
                    acc[mf][nf] = __builtin_amdgcn_mfma_f32_16x16x32_f16(af[mf], bg, acc[mf][nf], 0, 0, 0);
            }
        }
        __builtin_amdgcn_s_setprio(0);
        __syncthreads();
    }

#pragma unroll
    for (int nf = 0; nf < 5; ++nf) {
        int col = n0 + wn * 80 + nf * 16 + (lane & 15);
        float s = 0.f, ss = 0.f;
#pragma unroll
        for (int mf = 0; mf < 4; ++mf) {
#pragma unroll
            for (int i = 0; i < 4; ++i) {
                float vr = h2f(f2h(acc[mf][nf][i]));
                s += vr;
                ss += vr * vr;
            }
        }
        s += __shfl_xor(s, 16); s += __shfl_xor(s, 32);
        ss += __shfl_xor(ss, 16); ss += __shfl_xor(ss, 32);
        if (lane < 16) {
            atomicAdd(&stats[col], s);
            atomicAdd(&stats[statN + col], ss);
        }
    }

    unsigned short* T = smem;
#pragma unroll
    for (int half = 0; half < 2; ++half) {
        __syncthreads();
        if (wm == half) {
#pragma unroll
            for (int nf = 0; nf < 5; ++nf) {
                int col = wn * 80 + nf * 16 + (lane & 15);
#pragma unroll
                for (int mf = 0; mf < 4; ++mf) {
                    int r = mf * 16 + ((lane >> 4) << 2);
#pragma unroll
                    for (int i = 0; i < 4; ++i)
                        T[(r + i) * TLD + col] = f2h(acc[mf][nf][i]);
                }
            }
        }
        __syncthreads();
        int rowbase = m0 + half * 64;
#pragma unroll
        for (int p = 0; p < 5; ++p) {
            int cid = p * 512 + tid;
            int r = cid / 40, c16 = cid % 40;
            uint4v v = *(const uint4v*)&T[r * TLD + c16 * 8];
            *(uint4v*)&C[(size_t)(rowbase + r) * ldc + n0 + c16 * 8] = v;
        }
    }
}

// ---------------- k_gemm_dma: A via global_load_lds (142 us) ----------------
__launch_bounds__(512, 2)
__global__ void k_gemm_dma(const unsigned short* __restrict__ A, int lda, int kIters,
                           const unsigned short* __restrict__ B,
                           unsigned short* __restrict__ C, int ldc,
                           float* __restrict__ stats, int statN) {
    __shared__ unsigned short smem[128 * 64 + 320 * 64];
    unsigned short* As = smem;
    unsigned short* Bs = smem + 128 * 64;
    int tid = threadIdx.x;
    int lane = tid & 63, wid = tid >> 6;
    int wm = wid >> 2, wn = wid & 3;
    int m0 = blockIdx.y * 128;
    int n0 = blockIdx.x * 320;
    const unsigned short* Bb = B + (size_t)n0 * lda;
    const unsigned short* Ab = A + (size_t)m0 * lda;

    int brow8 = lane >> 3;
    int bc16 = (lane & 7) ^ brow8;

    f32x4 acc[4][5] = {};

    for (int kt = 0; kt < kIters; ++kt) {
        int k0 = kt * 64;
#pragma unroll
        for (int j = 0; j < 5; ++j) {
            int chunk = wid * 5 + j;
            int n = chunk * 8 + brow8;
            const unsigned short* g = Bb + (size_t)n * lda + k0 + bc16 * 8;
            __builtin_amdgcn_global_load_lds(
                (const __attribute__((address_space(1))) unsigned int*)g,
                (__attribute__((address_space(3))) unsigned int*)&Bs[chunk * 512], 16, 0, 0);
        }
#pragma unroll
        for (int j = 0; j < 2; ++j) {
            int chunk = wid * 2 + j;
            int row = chunk * 8 + brow8;
            const unsigned short* g = Ab + (size_t)row * lda + k0 + bc16 * 8;
            __builtin_amdgcn_global_load_lds(
                (const __attribute__((address_space(1))) unsigned int*)g,
                (__attribute__((address_space(3))) unsigned int*)&As[chunk * 512], 16, 0, 0);
        }
        __syncthreads();
        __builtin_amdgcn_s_setprio(1);
#pragma unroll
        for (int ks = 0; ks < 2; ++ks) {
            f16x8 af[4];
#pragma unroll
            for (int mf = 0; mf < 4; ++mf) {
                int ra = wm * 64 + mf * 16 + (lane & 15);
                int c16 = (ks * 4 + (lane >> 4)) ^ (ra & 7);
                af[mf] = *(const f16x8*)&As[ra * 64 + c16 * 8];
            }
#pragma unroll
            for (int nf = 0; nf < 5; ++nf) {
                int rb = wn * 80 + nf * 16 + (lane & 15);
                int c16 = (ks * 4 + (lane >> 4)) ^ (rb & 7);
                f16x8 bg = *(const f16x8*)&Bs[rb * 64 + c16 * 8];
#pragma unroll
                for (int mf = 0; mf < 4; ++mf)
                    acc[mf][nf] = __builtin_amdgcn_mfma_f32_16x16x32_f16(af[mf], bg, acc[mf][nf], 0, 0, 0);
            }
        }
        __builtin_amdgcn_s_setprio(0);
        __syncthreads();
    }

#pragma unroll
    for (int nf = 0; nf < 5; ++nf) {
        int col = n0 + wn * 80 + nf * 16 + (lane & 15);
        float s = 0.f, ss = 0.f;
#pragma unroll
        for (int mf = 0; mf < 4; ++mf) {
#pragma unroll
            for (int i = 0; i < 4; ++i) {
                float vr = h2f(f2h(acc[mf][nf][i]));
                s += vr;
                ss += vr * vr;
            }
        }
        s += __shfl_xor(s, 16); s += __shfl_xor(s, 32);
        ss += __shfl_xor(ss, 16); ss += __shfl_xor(ss, 32);
        if (lane < 16) {
            atomicAdd(&stats[col], s);
            atomicAdd(&stats[statN + col], ss);
        }
    }

    unsigned short* T = smem;
#pragma unroll
    for (int half = 0; half < 2; ++half) {
        __syncthreads();
        if (wm == half) {
#pragma unroll
            for (int nf = 0; nf < 5; ++nf) {
                int col = wn * 80 + nf * 16 + (lane & 15);
#pragma unroll
                for (int mf = 0; mf < 4; ++mf) {
                    int r = mf * 16 + ((lane >> 4) << 2);
#pragma unroll
                    for (int i = 0; i < 4; ++i)
                        T[(r + i) * TLD + col] = f2h(acc[mf][nf][i]);
                }
            }
        }
        __syncthreads();
        int rowbase = m0 + half * 64;
#pragma unroll
        for (int p = 0; p < 5; ++p) {
            int cid = p * 512 + tid;
            int r = cid / 40, c16 = cid % 40;
            uint4v v = *(const uint4v*)&T[r * TLD + c16 * 8];
            *(uint4v*)&C[(size_t)(rowbase + r) * ldc + n0 + c16 * 8] = v;
        }
    }
}

// ---------------- BN scale/shift from stats; optionally zeros the next stats buffer ----------------
__global__ void k_bnprep(const float* __restrict__ stats, int statN, int realN,
                         const float* __restrict__ g, const float* __restrict__ b,
                         float* __restrict__ sc, float* __restrict__ sh,
                         unsigned short* __restrict__ scH, unsigned short* __restrict__ shH,
                         float* __restrict__ zbuf, int zn) {
    int n = blockIdx.x * 256 + threadIdx.x;
    if (n < zn) zbuf[n] = 0.f;
    if (n >= statN) return;
    float scv = 0.f, shv = 0.f;
    if (n < realN) {
        float mu = stats[n] * (1.f / NN);
        float var = stats[statN + n] * (1.f / NN) - mu * mu;
        var = fmaxf(var, 0.f);
        float rs = rsqrtf(var + BN_EPS);
        scv = g[n] * rs;
        shv = b[n] - mu * scv;
    }
    sc[n] = scv;
    sh[n] = shv;
    scH[n] = f2h(scv);
    shH[n] = f2h(shv);
}

// ---------------- final output ----------------
__global__ void k_out(const unsigned short* __restrict__ u2, const float* __restrict__ sc,
                      const float* __restrict__ sh, float* __restrict__ out) {
    unsigned int idx = blockIdx.x * 256u + threadIdx.x;
    if (idx >= (unsigned int)NN * DD) return;
    unsigned int n = idx / DD, d = idx % DD;
    out[idx] = sc[d] * h2f(u2[(size_t)n * DP + d]) + sh[d];
}

extern "C" void kernel_launch(void* const* d_in, const int* in_sizes, int n_in,
                              void* d_out, int out_size, void* d_ws, size_t ws_size,
                              hipStream_t stream) {
    const int* x = (const int*)d_in[0];
    const int* ei = (const int*)d_in[1];
    const int* ea = (const int*)d_in[2];
    const float* xe1 = (const float*)d_in[3];
    const float* xe2 = (const float*)d_in[4];
    const float* ee1 = (const float*)d_in[5];
    const float* ee2 = (const float*)d_in[6];
    const float* W1 = (const float*)d_in[7];
    const float* bn1g = (const float*)d_in[9];
    const float* bn1b = (const float*)d_in[10];
    const float* W2 = (const float*)d_in[11];
    const float* bng = (const float*)d_in[13];
    const float* bnb = (const float*)d_in[14];
    float* out = (float*)d_out;

    char* ws = (char*)d_ws;
    size_t off = 0;
    auto alloc = [&](size_t bytes) -> void* {
        void* p = ws + off;
        off += (bytes + 255) & ~(size_t)255;
        return p;
    };
    unsigned short* hbuf = (unsigned short*)alloc((size_t)NN * DP * 2);   // h0 / u2
    unsigned short* agg  = (unsigned short*)alloc((size_t)NN * DP * 2);
    unsigned short* u1   = (unsigned short*)alloc((size_t)NN * D2P * 2);
    unsigned short* W1t  = (unsigned short*)alloc((size_t)NL * D2P * DP * 2);
    unsigned short* W2t  = (unsigned short*)alloc((size_t)NL * DP * D2P * 2);
    unsigned short* eec  = (unsigned short*)alloc((size_t)NL * 15 * DP * 2);
    int* row_ptr = (int*)alloc((size_t)(NN + 1) * 4);
    int* cursor  = (int*)alloc((size_t)NN * 4);
    int* counts  = (int*)alloc((size_t)NN * 4);
    int* srcs    = (int*)alloc((size_t)NE * 4);
    int* combos  = (int*)alloc((size_t)NE * 4);
    int* partial  = (int*)alloc(512 * 4);
    int* partial2 = (int*)alloc(512 * 4);
    float* stats1 = (float*)alloc(2 * D2P * 4);
    float* stats2 = (float*)alloc(2 * DP * 4);
    float* sc1 = (float*)alloc(D2P * 4);
    float* sh1 = (float*)alloc(D2P * 4);
    float* sc2 = (float*)alloc(DP * 4);
    float* sh2 = (float*)alloc(DP * 4);
    unsigned short* scH1 = (unsigned short*)alloc(D2P * 2);
    unsigned short* shH1 = (unsigned short*)alloc(D2P * 2);
    unsigned short* scH2 = (unsigned short*)alloc(DP * 2);
    unsigned short* shH2 = (unsigned short*)alloc(DP * 2);

    // prep
    k_w1t<<<NL * D2P * DP / 256, 256, 0, stream>>>(W1, W1t);
    k_w2t<<<NL * DP * D2P / 256, 256, 0, stream>>>(W2, W2t);
    k_eec<<<(NL * 15 * DP + 255) / 256, 256, 0, stream>>>(ee1, ee2, eec);
    k_h0<<<NN * DP / 256, 256, 0, stream>>>(x, xe1, xe2, hbuf);

    // CSR
    hipMemsetAsync(counts, 0, (size_t)NN * 4, stream);
    k_count<<<NE / 256, 256, 0, stream>>>(ei, counts);
    k_scan1<<<NN / 256, 256, 0, stream>>>(counts, partial);
    k_scan2<<<1, 512, 0, stream>>>(partial, partial2);
    k_scan3<<<NN / 256, 256, 0, stream>>>(counts, partial2, row_ptr, cursor);
    k_fill<<<NE / 256, 256, 0, stream>>>(ei, ea, cursor, srcs, combos);

    const unsigned short* hcur = hbuf;
    const float* scIn = nullptr;   // layer 0: identity (no affine)
    const float* shIn = nullptr;
    int reluIn = 0;
    for (int l = 0; l < NL; ++l) {
        // gather also zeros stats1 (block 0) — replaces hipMemsetAsync
        k_gather<<<NN * 40 / 256, 256, 0, stream>>>(hcur, scIn, shIn, reluIn, row_ptr, srcs,
                                                    combos, eec + (size_t)l * 15 * DP, agg,
                                                    stats1, 2 * D2P);
        dim3 g1(D2P / 320, NN / 128);
        k_gemm_dma<<<g1, 512, 0, stream>>>(agg, DP, DP / 64,
                                           W1t + (size_t)l * D2P * DP, u1, D2P, stats1, D2P);
        // bnprep(stats1) also zeros stats2 — replaces hipMemsetAsync
        k_bnprep<<<(D2P + 255) / 256, 256, 0, stream>>>(stats1, D2P, D2, bn1g + (size_t)l * D2,
                                                        bn1b + (size_t)l * D2, sc1, sh1, scH1, shH1,
                                                        stats2, 2 * DP);
        dim3 g2(DP / 320, NN / 128);
        k_gemm_r4<<<g2, 512, 0, stream>>>(u1, D2P, D2P / 64, scH1, shH1,
                                          W2t + (size_t)l * DP * D2P, hbuf, DP, stats2, DP);
        k_bnprep<<<(DP + 255) / 256, 256, 0, stream>>>(stats2, DP, DD, bng + (size_t)l * DD,
                                                       bnb + (size_t)l * DD, sc2, sh2, scH2, shH2,
                                                       nullptr, 0);
        hcur = hbuf;
        scIn = sc2;
        shIn = sh2;
        reluIn = 1;
    }
    k_out<<<(unsigned int)NN * DD / 256, 256, 0, stream>>>(hbuf, sc2, sh2, out);
}

// Round 21
// 1785.515 us; speedup vs baseline: 1.2738x; 1.0115x over previous
//
#include <hip/hip_runtime.h>
#include <hip/hip_bf16.h>
#include <stdint.h>

#define NN 131072
#define NE 262144
#define DD 300
#define DP 320
#define D2 600
#define D2P 640
#define NL 5
#define BN_EPS 1e-5f

typedef __attribute__((ext_vector_type(8))) _Float16 f16x8;
typedef __attribute__((ext_vector_type(4))) float f32x4;
typedef __attribute__((ext_vector_type(4))) unsigned int uint4v;
typedef __attribute__((ext_vector_type(4))) unsigned short u16x4;

static __device__ __forceinline__ float h2f(unsigned short u) {
    union { unsigned short u; _Float16 h; } c; c.u = u; return (float)c.h;
}
static __device__ __forceinline__ unsigned short f2h(float f) {
    union { unsigned short u; _Float16 h; } c; c.h = (_Float16)f; return c.u;
}

// ---------------- prep kernels ----------------

__global__ void k_w1t(const float* __restrict__ W1, unsigned short* __restrict__ W1t) {
    int idx = blockIdx.x * 256 + threadIdx.x;
    if (idx >= NL * D2P * DP) return;
    int l = idx / (D2P * DP);
    int r = idx % (D2P * DP);
    int n = r / DP, k = r % DP;
    float v = (n < D2 && k < DD) ? W1[(size_t)(l * DD + k) * D2 + n] : 0.f;
    W1t[idx] = f2h(v);
}

__global__ void k_w2t(const float* __restrict__ W2, unsigned short* __restrict__ W2t) {
    int idx = blockIdx.x * 256 + threadIdx.x;
    if (idx >= NL * DP * D2P) return;
    int l = idx / (DP * D2P);
    int r = idx % (DP * D2P);
    int n = r / D2P, k = r % D2P;
    float v = (n < DD && k < D2) ? W2[(size_t)(l * D2 + k) * DD + n] : 0.f;
    W2t[idx] = f2h(v);
}

__global__ void k_eec(const float* __restrict__ ee1, const float* __restrict__ ee2,
                      unsigned short* __restrict__ eec) {
    int idx = blockIdx.x * 256 + threadIdx.x;
    if (idx >= NL * 15 * DP) return;
    int l = idx / (15 * DP);
    int r = idx % (15 * DP);
    int cb = r / DP, c = r % DP;
    int b = cb / 3, d = cb % 3;
    float v = 0.f;
    if (c < DD) v = ee1[(size_t)(l * 5 + b) * DD + c] + ee2[(size_t)(l * 3 + d) * DD + c];
    eec[idx] = f2h(v);
}

__global__ void k_h0(const int* __restrict__ x, const float* __restrict__ xe1,
                     const float* __restrict__ xe2, unsigned short* __restrict__ h) {
    unsigned int idx = blockIdx.x * 256u + threadIdx.x;
    if (idx >= (unsigned int)NN * DP) return;
    unsigned int n = idx / DP, c = idx % DP;
    float v = 0.f;
    if (c < DD) v = xe1[(size_t)x[2 * n] * DD + c] + xe2[(size_t)x[2 * n + 1] * DD + c];
    h[idx] = f2h(v);
}

// ---------------- CSR build ----------------

__global__ void k_count(const int* __restrict__ ei, int* __restrict__ counts) {
    int e = blockIdx.x * 256 + threadIdx.x;
    if (e < NE) atomicAdd(&counts[ei[NE + e]], 1);
}

__global__ void k_scan1(const int* __restrict__ counts, int* __restrict__ partial) {
    __shared__ int sm[256];
    int t = threadIdx.x;
    sm[t] = counts[blockIdx.x * 256 + t];
    __syncthreads();
    for (int o = 128; o > 0; o >>= 1) {
        if (t < o) sm[t] += sm[t + o];
        __syncthreads();
    }
    if (t == 0) partial[blockIdx.x] = sm[0];
}

__global__ void k_scan2(const int* __restrict__ partial, int* __restrict__ partial2) {
    __shared__ int sm[512];
    int t = threadIdx.x;
    int v = partial[t];
    sm[t] = v;
    __syncthreads();
    for (int o = 1; o < 512; o <<= 1) {
        int add = (t >= o) ? sm[t - o] : 0;
        __syncthreads();
        sm[t] += add;
        __syncthreads();
    }
    partial2[t] = sm[t] - v;  // exclusive
}

__global__ void k_scan3(const int* __restrict__ counts, const int* __restrict__ partial2,
                        int* __restrict__ row_ptr, int* __restrict__ cursor) {
    __shared__ int sm[256];
    int t = threadIdx.x;
    int i = blockIdx.x * 256 + t;
    int v = counts[i];
    sm[t] = v;
    __syncthreads();
    for (int o = 1; o < 256; o <<= 1) {
        int add = (t >= o) ? sm[t - o] : 0;
        __syncthreads();
        sm[t] += add;
        __syncthreads();
    }
    int excl = partial2[blockIdx.x] + sm[t] - v;
    row_ptr[i] = excl;
    cursor[i] = excl;
    if (i == NN - 1) row_ptr[NN] = excl + v;
}

__global__ void k_fill(const int* __restrict__ ei, const int* __restrict__ ea,
                       int* __restrict__ cursor, int* __restrict__ srcs,
                       int* __restrict__ combos) {
    int e = blockIdx.x * 256 + threadIdx.x;
    if (e >= NE) return;
    int d = ei[NE + e];
    int pos = atomicAdd(&cursor[d], 1);
    srcs[pos] = ei[e];
    combos[pos] = ea[2 * e] * 3 + ea[2 * e + 1];
}

// ---------------- aggregation (pull, CSR); block 0 also zeros the stats buffer ----------------
__global__ void k_gather(const unsigned short* __restrict__ h, const float* __restrict__ sc,
                         const float* __restrict__ sh, int relu,
                         const int* __restrict__ row_ptr, const int* __restrict__ srcs,
                         const int* __restrict__ combos, const unsigned short* __restrict__ eec,
                         unsigned short* __restrict__ agg,
                         float* __restrict__ stz, int stzN) {
    if (blockIdx.x == 0) {
        for (int i = threadIdx.x; i < stzN; i += 256) stz[i] = 0.f;
    }
    unsigned int idx = blockIdx.x * 256u + threadIdx.x;  // N*40 chunks of 8 cols
    if (idx >= (unsigned int)NN * 40) return;
    unsigned int m = idx / 40;
    unsigned int j = idx % 40;
    int c0 = j * 8;
    bool aff = (sc != nullptr);
    float a[8] = {0, 0, 0, 0, 0, 0, 0, 0};
    float scv[8], shv[8];
    if (aff) {
#pragma unroll
        for (int i = 0; i < 8; i++) { scv[i] = sc[c0 + i]; shv[i] = sh[c0 + i]; }
    }
    int e0 = row_ptr[m], e1 = row_ptr[m + 1];
    for (int e = e0; e < e1; ++e) {
        int s = srcs[e], cb = combos[e];
        uint4v hv = *(const uint4v*)(h + (size_t)s * DP + c0);
        uint4v ev = *(const uint4v*)(eec + (size_t)cb * DP + c0);
        const unsigned short* hp = (const unsigned short*)&hv;
        const unsigned short* ep = (const unsigned short*)&ev;
#pragma unroll
        for (int i = 0; i < 8; i++) {
            float f = h2f(hp[i]);
            if (aff) {
                f = scv[i] * f + shv[i];
                if (relu) f = fmaxf(f, 0.f);
            }
            a[i] += f + h2f(ep[i]);
        }
    }
    unsigned short o[8];
#pragma unroll
    for (int i = 0; i < 8; i++) o[i] = f2h(a[i]);
    *(uint4v*)(agg + (size_t)m * DP + c0) = *(const uint4v*)o;
}

// ---------------- k_gemm_r4: reg-staged A + affine fold (142 us) ----------------
#define TLD 328
__launch_bounds__(512, 2)
__global__ void k_gemm_r4(const unsigned short* __restrict__ A, int lda, int kIters,
                          const unsigned short* __restrict__ scH,
                          const unsigned short* __restrict__ shH,
                          const unsigned short* __restrict__ B,
                          unsigned short* __restrict__ C, int ldc,
                          float* __restrict__ stats, int statN) {
    __shared__ unsigned short smem[128 * 64 + 320 * 64];
    unsigned short* As = smem;
    unsigned short* Bs = smem + 128 * 64;
    int tid = threadIdx.x;
    int lane = tid & 63, wid = tid >> 6;
    int wm = wid >> 2, wn = wid & 3;
    int m0 = blockIdx.y * 128;
    int n0 = blockIdx.x * 320;
    const unsigned short* Bb = B + (size_t)n0 * lda;

    int srow = tid >> 2;
    int sc16 = tid & 3;
    int swz = srow & 7;
    const unsigned short* aRow = A + (size_t)(m0 + srow) * lda;
    int brow8 = lane >> 3;
    int bc16 = (lane & 7) ^ brow8;

    f32x4 acc[4][5] = {};

    for (int kt = 0; kt < kIters; ++kt) {
        int k0 = kt * 64;
#pragma unroll
        for (int j = 0; j < 5; ++j) {
            int chunk = wid * 5 + j;
            int n = chunk * 8 + brow8;
            const unsigned short* g = Bb + (size_t)n * lda + k0 + bc16 * 8;
            __builtin_amdgcn_global_load_lds(
                (const __attribute__((address_space(1))) unsigned int*)g,
                (__attribute__((address_space(3))) unsigned int*)&Bs[chunk * 512], 16, 0, 0);
        }
        uint4v v0 = *(const uint4v*)(aRow + k0 + sc16 * 8);
        uint4v v1 = *(const uint4v*)(aRow + k0 + (sc16 + 4) * 8);
        if (scH) {
            f16x8 a0 = *(f16x8*)&v0, a1 = *(f16x8*)&v1;
            f16x8 s0 = *(const f16x8*)&scH[k0 + sc16 * 8];
            f16x8 h0 = *(const f16x8*)&shH[k0 + sc16 * 8];
            f16x8 s1 = *(const f16x8*)&scH[k0 + (sc16 + 4) * 8];
            f16x8 h1 = *(const f16x8*)&shH[k0 + (sc16 + 4) * 8];
#pragma unroll
            for (int i = 0; i < 8; i++) {
                _Float16 t0 = a0[i] * s0[i] + h0[i];
                _Float16 t1 = a1[i] * s1[i] + h1[i];
                a0[i] = t0 > (_Float16)0 ? t0 : (_Float16)0;
                a1[i] = t1 > (_Float16)0 ? t1 : (_Float16)0;
            }
            v0 = *(uint4v*)&a0;
            v1 = *(uint4v*)&a1;
        }
        *(uint4v*)&As[srow * 64 + ((sc16 ^ swz) * 8)] = v0;
        *(uint4v*)&As[srow * 64 + (((sc16 + 4) ^ swz) * 8)] = v1;
        __syncthreads();
        __builtin_amdgcn_s_setprio(1);
#pragma unroll
        for (int ks = 0; ks < 2; ++ks) {
            f16x8 af[4];
#pragma unroll
            for (int mf = 0; mf < 4; ++mf) {
                int ra = wm * 64 + mf * 16 + (lane & 15);
                int c16 = (ks * 4 + (lane >> 4)) ^ (ra & 7);
                af[mf] = *(const f16x8*)&As[ra * 64 + c16 * 8];
            }
#pragma unroll
            for (int nf = 0; nf < 5; ++nf) {
                int rb = wn * 80 + nf * 16 + (lane & 15);
                int c16 = (ks * 4 + (lane >> 4)) ^ (rb & 7);
                f16x8 bg = *(const f16x8*)&Bs[rb * 64 + c16 * 8];
#pragma unroll
                for (int mf = 0; mf < 4; ++mf)
                    acc[mf][nf] = __builtin_amdgcn_mfma_f32_16x16x32_f16(af[mf], bg, acc[mf][nf], 0, 0, 0);
            }
        }
        __builtin_amdgcn_s_setprio(0);
        __syncthreads();
    }

#pragma unroll
    for (int nf = 0; nf < 5; ++nf) {
        int col = n0 + wn * 80 + nf * 16 + (lane & 15);
        float s = 0.f, ss = 0.f;
#pragma unroll
        for (int mf = 0; mf < 4; ++mf) {
#pragma unroll
            for (int i = 0; i < 4; ++i) {
                float vr = h2f(f2h(acc[mf][nf][i]));
                s += vr;
                ss += vr * vr;
            }
        }
        s += __shfl_xor(s, 16); s += __shfl_xor(s, 32);
        ss += __shfl_xor(ss, 16); ss += __shfl_xor(ss, 32);
        if (lane < 16) {
            atomicAdd(&stats[col], s);
            atomicAdd(&stats[statN + col], ss);
        }
    }

    unsigned short* T = smem;
#pragma unroll
    for (int half = 0; half < 2; ++half) {
        __syncthreads();
        if (wm == half) {
#pragma unroll
            for (int nf = 0; nf < 5; ++nf) {
                int col = wn * 80 + nf * 16 + (lane & 15);
#pragma unroll
                for (int mf = 0; mf < 4; ++mf) {
                    int r = mf * 16 + ((lane >> 4) << 2);
#pragma unroll
                    for (int i = 0; i < 4; ++i)
                        T[(r + i) * TLD + col] = f2h(acc[mf][nf][i]);
                }
            }
        }
        __syncthreads();
        int rowbase = m0 + half * 64;
#pragma unroll
        for (int p = 0; p < 5; ++p) {
            int cid = p * 512 + tid;
            int r = cid / 40, c16 = cid % 40;
            uint4v v = *(const uint4v*)&T[r * TLD + c16 * 8];
            *(uint4v*)&C[(size_t)(rowbase + r) * ldc + n0 + c16 * 8] = v;
        }
    }
}

// ---------------- k_gemm_dma: A via global_load_lds (142 us) ----------------
__launch_bounds__(512, 2)
__global__ void k_gemm_dma(const unsigned short* __restrict__ A, int lda, int kIters,
                           const unsigned short* __restrict__ B,
                           unsigned short* __restrict__ C, int ldc,
                           float* __restrict__ stats, int statN) {
    __shared__ unsigned short smem[128 * 64 + 320 * 64];
    unsigned short* As = smem;
    unsigned short* Bs = smem + 128 * 64;
    int tid = threadIdx.x;
    int lane = tid & 63, wid = tid >> 6;
    int wm = wid >> 2, wn = wid & 3;
    int m0 = blockIdx.y * 128;
    int n0 = blockIdx.x * 320;
    const unsigned short* Bb = B + (size_t)n0 * lda;
    const unsigned short* Ab = A + (size_t)m0 * lda;

    int brow8 = lane >> 3;
    int bc16 = (lane & 7) ^ brow8;

    f32x4 acc[4][5] = {};

    for (int kt = 0; kt < kIters; ++kt) {
        int k0 = kt * 64;
#pragma unroll
        for (int j = 0; j < 5; ++j) {
            int chunk = wid * 5 + j;
            int n = chunk * 8 + brow8;
            const unsigned short* g = Bb + (size_t)n * lda + k0 + bc16 * 8;
            __builtin_amdgcn_global_load_lds(
                (const __attribute__((address_space(1))) unsigned int*)g,
                (__attribute__((address_space(3))) unsigned int*)&Bs[chunk * 512], 16, 0, 0);
        }
#pragma unroll
        for (int j = 0; j < 2; ++j) {
            int chunk = wid * 2 + j;
            int row = chunk * 8 + brow8;
            const unsigned short* g = Ab + (size_t)row * lda + k0 + bc16 * 8;
            __builtin_amdgcn_global_load_lds(
                (const __attribute__((address_space(1))) unsigned int*)g,
                (__attribute__((address_space(3))) unsigned int*)&As[chunk * 512], 16, 0, 0);
        }
        __syncthreads();
        __builtin_amdgcn_s_setprio(1);
#pragma unroll
        for (int ks = 0; ks < 2; ++ks) {
            f16x8 af[4];
#pragma unroll
            for (int mf = 0; mf < 4; ++mf) {
                int ra = wm * 64 + mf * 16 + (lane & 15);
                int c16 = (ks * 4 + (lane >> 4)) ^ (ra & 7);
                af[mf] = *(const f16x8*)&As[ra * 64 + c16 * 8];
            }
#pragma unroll
            for (int nf = 0; nf < 5; ++nf) {
                int rb = wn * 80 + nf * 16 + (lane & 15);
                int c16 = (ks * 4 + (lane >> 4)) ^ (rb & 7);
                f16x8 bg = *(const f16x8*)&Bs[rb * 64 + c16 * 8];
#pragma unroll
                for (int mf = 0; mf < 4; ++mf)
                    acc[mf][nf] = __builtin_amdgcn_mfma_f32_16x16x32_f16(af[mf], bg, acc[mf][nf], 0, 0, 0);
            }
        }
        __builtin_amdgcn_s_setprio(0);
        __syncthreads();
    }

#pragma unroll
    for (int nf = 0; nf < 5; ++nf) {
        int col = n0 + wn * 80 + nf * 16 + (lane & 15);
        float s = 0.f, ss = 0.f;
#pragma unroll
        for (int mf = 0; mf < 4; ++mf) {
#pragma unroll
            for (int i = 0; i < 4; ++i) {
                float vr = h2f(f2h(acc[mf][nf][i]));
                s += vr;
                ss += vr * vr;
            }
        }
        s += __shfl_xor(s, 16); s += __shfl_xor(s, 32);
        ss += __shfl_xor(ss, 16); ss += __shfl_xor(ss, 32);
        if (lane < 16) {
            atomicAdd(&stats[col], s);
            atomicAdd(&stats[statN + col], ss);
        }
    }

    unsigned short* T = smem;
#pragma unroll
    for (int half = 0; half < 2; ++half) {
        __syncthreads();
        if (wm == half) {
#pragma unroll
            for (int nf = 0; nf < 5; ++nf) {
                int col = wn * 80 + nf * 16 + (lane & 15);
#pragma unroll
                for (int mf = 0; mf < 4; ++mf) {
                    int r = mf * 16 + ((lane >> 4) << 2);
#pragma unroll
                    for (int i = 0; i < 4; ++i)
                        T[(r + i) * TLD + col] = f2h(acc[mf][nf][i]);
                }
            }
        }
        __syncthreads();
        int rowbase = m0 + half * 64;
#pragma unroll
        for (int p = 0; p < 5; ++p) {
            int cid = p * 512 + tid;
            int r = cid / 40, c16 = cid % 40;
            uint4v v = *(const uint4v*)&T[r * TLD + c16 * 8];
            *(uint4v*)&C[(size_t)(rowbase + r) * ldc + n0 + c16 * 8] = v;
        }
    }
}

// ---------------- BN scale/shift from stats; optionally zeros the next stats buffer ----------------
__global__ void k_bnprep(const float* __restrict__ stats, int statN, int realN,
                         const float* __restrict__ g, const float* __restrict__ b,
                         float* __restrict__ sc, float* __restrict__ sh,
                         unsigned short* __restrict__ scH, unsigned short* __restrict__ shH,
                         float* __restrict__ zbuf, int zn) {
    int n = blockIdx.x * 256 + threadIdx.x;
    if (n < zn) zbuf[n] = 0.f;
    if (n >= statN) return;
    float scv = 0.f, shv = 0.f;
    if (n < realN) {
        float mu = stats[n] * (1.f / NN);
        float var = stats[statN + n] * (1.f / NN) - mu * mu;
        var = fmaxf(var, 0.f);
        float rs = rsqrtf(var + BN_EPS);
        scv = g[n] * rs;
        shv = b[n] - mu * scv;
    }
    sc[n] = scv;
    sh[n] = shv;
    scH[n] = f2h(scv);
    shH[n] = f2h(shv);
}

// ---------------- final output: vectorized x4 (300 = 75 x 4, rows float4-aligned) ----------------
__global__ void k_out(const unsigned short* __restrict__ u2, const float* __restrict__ sc,
                      const float* __restrict__ sh, float* __restrict__ out) {
    unsigned int idx = blockIdx.x * 256u + threadIdx.x;
    if (idx >= (unsigned int)NN * 75) return;
    unsigned int n = idx / 75, q = idx % 75;
    int d = q * 4;
    u16x4 hv = *(const u16x4*)(u2 + (size_t)n * DP + d);
    f32x4 o;
#pragma unroll
    for (int i = 0; i < 4; ++i)
        o[i] = sc[d + i] * h2f(hv[i]) + sh[d + i];
    *(f32x4*)(out + (size_t)n * DD + d) = o;
}

extern "C" void kernel_launch(void* const* d_in, const int* in_sizes, int n_in,
                              void* d_out, int out_size, void* d_ws, size_t ws_size,
                              hipStream_t stream) {
    const int* x = (const int*)d_in[0];
    const int* ei = (const int*)d_in[1];
    const int* ea = (const int*)d_in[2];
    const float* xe1 = (const float*)d_in[3];
    const float* xe2 = (const float*)d_in[4];
    const float* ee1 = (const float*)d_in[5];
    const float* ee2 = (const float*)d_in[6];
    const float* W1 = (const float*)d_in[7];
    const float* bn1g = (const float*)d_in[9];
    const float* bn1b = (const float*)d_in[10];
    const float* W2 = (const float*)d_in[11];
    const float* bng = (const float*)d_in[13];
    const float* bnb = (const float*)d_in[14];
    float* out = (float*)d_out;

    char* ws = (char*)d_ws;
    size_t off = 0;
    auto alloc = [&](size_t bytes) -> void* {
        void* p = ws + off;
        off += (bytes + 255) & ~(size_t)255;
        return p;
    };
    unsigned short* hbuf = (unsigned short*)alloc((size_t)NN * DP * 2);   // h0 / u2
    unsigned short* agg  = (unsigned short*)alloc((size_t)NN * DP * 2);
    unsigned short* u1   = (unsigned short*)alloc((size_t)NN * D2P * 2);
    unsigned short* W1t  = (unsigned short*)alloc((size_t)NL * D2P * DP * 2);
    unsigned short* W2t  = (unsigned short*)alloc((size_t)NL * DP * D2P * 2);
    unsigned short* eec  = (unsigned short*)alloc((size_t)NL * 15 * DP * 2);
    int* row_ptr = (int*)alloc((size_t)(NN + 1) * 4);
    int* cursor  = (int*)alloc((size_t)NN * 4);
    int* counts  = (int*)alloc((size_t)NN * 4);
    int* srcs    = (int*)alloc((size_t)NE * 4);
    int* combos  = (int*)alloc((size_t)NE * 4);
    int* partial  = (int*)alloc(512 * 4);
    int* partial2 = (int*)alloc(512 * 4);
    float* stats1 = (float*)alloc(2 * D2P * 4);
    float* stats2 = (float*)alloc(2 * DP * 4);
    float* sc1 = (float*)alloc(D2P * 4);
    float* sh1 = (float*)alloc(D2P * 4);
    float* sc2 = (float*)alloc(DP * 4);
    float* sh2 = (float*)alloc(DP * 4);
    unsigned short* scH1 = (unsigned short*)alloc(D2P * 2);
    unsigned short* shH1 = (unsigned short*)alloc(D2P * 2);
    unsigned short* scH2 = (unsigned short*)alloc(DP * 2);
    unsigned short* shH2 = (unsigned short*)alloc(DP * 2);

    // prep
    k_w1t<<<NL * D2P * DP / 256, 256, 0, stream>>>(W1, W1t);
    k_w2t<<<NL * DP * D2P / 256, 256, 0, stream>>>(W2, W2t);
    k_eec<<<(NL * 15 * DP + 255) / 256, 256, 0, stream>>>(ee1, ee2, eec);
    k_h0<<<NN * DP / 256, 256, 0, stream>>>(x, xe1, xe2, hbuf);

    // CSR
    hipMemsetAsync(counts, 0, (size_t)NN * 4, stream);
    k_count<<<NE / 256, 256, 0, stream>>>(ei, counts);
    k_scan1<<<NN / 256, 256, 0, stream>>>(counts, partial);
    k_scan2<<<1, 512, 0, stream>>>(partial, partial2);
    k_scan3<<<NN / 256, 256, 0, stream>>>(counts, partial2, row_ptr, cursor);
    k_fill<<<NE / 256, 256, 0, stream>>>(ei, ea, cursor, srcs, combos);

    const unsigned short* hcur = hbuf;
    const float* scIn = nullptr;   // layer 0: identity (no affine)
    const float* shIn = nullptr;
    int reluIn = 0;
    for (int l = 0; l < NL; ++l) {
        // gather also zeros stats1 (block 0)
        k_gather<<<NN * 40 / 256, 256, 0, stream>>>(hcur, scIn, shIn, reluIn, row_ptr, srcs,
                                                    combos, eec + (size_t)l * 15 * DP, agg,
                                                    stats1, 2 * D2P);
        dim3 g1(D2P / 320, NN / 128);
        k_gemm_dma<<<g1, 512, 0, stream>>>(agg, DP, DP / 64,
                                           W1t + (size_t)l * D2P * DP, u1, D2P, stats1, D2P);
        // bnprep(stats1) also zeros stats2
        k_bnprep<<<(D2P + 255) / 256, 256, 0, stream>>>(stats1, D2P, D2, bn1g + (size_t)l * D2,
                                                        bn1b + (size_t)l * D2, sc1, sh1, scH1, shH1,
                                                        stats2, 2 * DP);
        dim3 g2(DP / 320, NN / 128);
        k_gemm_r4<<<g2, 512, 0, stream>>>(u1, D2P, D2P / 64, scH1, shH1,
                                          W2t + (size_t)l * DP * D2P, hbuf, DP, stats2, DP);
        k_bnprep<<<(DP + 255) / 256, 256, 0, stream>>>(stats2, DP, DD, bng + (size_t)l * DD,
                                                       bnb + (size_t)l * DD, sc2, sh2, scH2, shH2,
                                                       nullptr, 0);
        hcur = hbuf;
        scIn = sc2;
        shIn = sh2;
        reluIn = 1;
    }
    k_out<<<NN * 75 / 256, 256, 0, stream>>>(hbuf, sc2, sh2, out);
}

// Round 22
// 1770.249 us; speedup vs baseline: 1.2848x; 1.0086x over previous
//
#include <hip/hip_runtime.h>
#include <hip/hip_bf16.h>
#include <stdint.h>

#define NN 131072
#define NE 262144
#define DD 300
#define DP 320
#define D2 600
#define D2P 640
#define NL 5
#define BN_EPS 1e-5f

typedef __attribute__((ext_vector_type(8))) _Float16 f16x8;
typedef __attribute__((ext_vector_type(4))) float f32x4;
typedef __attribute__((ext_vector_type(4))) unsigned int uint4v;
typedef __attribute__((ext_vector_type(4))) unsigned short u16x4;

static __device__ __forceinline__ float h2f(unsigned short u) {
    union { unsigned short u; _Float16 h; } c; c.u = u; return (float)c.h;
}
static __device__ __forceinline__ unsigned short f2h(float f) {
    union { unsigned short u; _Float16 h; } c; c.h = (_Float16)f; return c.u;
}

// ---------------- prep kernels ----------------

__global__ void k_w1t(const float* __restrict__ W1, unsigned short* __restrict__ W1t) {
    int idx = blockIdx.x * 256 + threadIdx.x;
    if (idx >= NL * D2P * DP) return;
    int l = idx / (D2P * DP);
    int r = idx % (D2P * DP);
    int n = r / DP, k = r % DP;
    float v = (n < D2 && k < DD) ? W1[(size_t)(l * DD + k) * D2 + n] : 0.f;
    W1t[idx] = f2h(v);
}

__global__ void k_w2t(const float* __restrict__ W2, unsigned short* __restrict__ W2t) {
    int idx = blockIdx.x * 256 + threadIdx.x;
    if (idx >= NL * DP * D2P) return;
    int l = idx / (DP * D2P);
    int r = idx % (DP * D2P);
    int n = r / D2P, k = r % D2P;
    float v = (n < DD && k < D2) ? W2[(size_t)(l * D2 + k) * DD + n] : 0.f;
    W2t[idx] = f2h(v);
}

__global__ void k_eec(const float* __restrict__ ee1, const float* __restrict__ ee2,
                      unsigned short* __restrict__ eec) {
    int idx = blockIdx.x * 256 + threadIdx.x;
    if (idx >= NL * 15 * DP) return;
    int l = idx / (15 * DP);
    int r = idx % (15 * DP);
    int cb = r / DP, c = r % DP;
    int b = cb / 3, d = cb % 3;
    float v = 0.f;
    if (c < DD) v = ee1[(size_t)(l * 5 + b) * DD + c] + ee2[(size_t)(l * 3 + d) * DD + c];
    eec[idx] = f2h(v);
}

__global__ void k_h0(const int* __restrict__ x, const float* __restrict__ xe1,
                     const float* __restrict__ xe2, unsigned short* __restrict__ h) {
    unsigned int idx = blockIdx.x * 256u + threadIdx.x;
    if (idx >= (unsigned int)NN * DP) return;
    unsigned int n = idx / DP, c = idx % DP;
    float v = 0.f;
    if (c < DD) v = xe1[(size_t)x[2 * n] * DD + c] + xe2[(size_t)x[2 * n + 1] * DD + c];
    h[idx] = f2h(v);
}

// ---------------- CSR build ----------------

__global__ void k_count(const int* __restrict__ ei, int* __restrict__ counts) {
    int e = blockIdx.x * 256 + threadIdx.x;
    if (e < NE) atomicAdd(&counts[ei[NE + e]], 1);
}

__global__ void k_scan1(const int* __restrict__ counts, int* __restrict__ partial) {
    __shared__ int sm[256];
    int t = threadIdx.x;
    sm[t] = counts[blockIdx.x * 256 + t];
    __syncthreads();
    for (int o = 128; o > 0; o >>= 1) {
        if (t < o) sm[t] += sm[t + o];
        __syncthreads();
    }
    if (t == 0) partial[blockIdx.x] = sm[0];
}

__global__ void k_scan2(const int* __restrict__ partial, int* __restrict__ partial2) {
    __shared__ int sm[512];
    int t = threadIdx.x;
    int v = partial[t];
    sm[t] = v;
    __syncthreads();
    for (int o = 1; o < 512; o <<= 1) {
        int add = (t >= o) ? sm[t - o] : 0;
        __syncthreads();
        sm[t] += add;
        __syncthreads();
    }
    partial2[t] = sm[t] - v;  // exclusive
}

__global__ void k_scan3(const int* __restrict__ counts, const int* __restrict__ partial2,
                        int* __restrict__ row_ptr, int* __restrict__ cursor) {
    __shared__ int sm[256];
    int t = threadIdx.x;
    int i = blockIdx.x * 256 + t;
    int v = counts[i];
    sm[t] = v;
    __syncthreads();
    for (int o = 1; o < 256; o <<= 1) {
        int add = (t >= o) ? sm[t - o] : 0;
        __syncthreads();
        sm[t] += add;
        __syncthreads();
    }
    int excl = partial2[blockIdx.x] + sm[t] - v;
    row_ptr[i] = excl;
    cursor[i] = excl;
    if (i == NN - 1) row_ptr[NN] = excl + v;
}

// edges packed as int2 {src, combo}: one 8B index load per edge in the gather
__global__ void k_fill(const int* __restrict__ ei, const int* __restrict__ ea,
                       int* __restrict__ cursor, int2* __restrict__ edges) {
    int e = blockIdx.x * 256 + threadIdx.x;
    if (e >= NE) return;
    int d = ei[NE + e];
    int pos = atomicAdd(&cursor[d], 1);
    edges[pos] = make_int2(ei[e], ea[2 * e] * 3 + ea[2 * e + 1]);
}

// ---------------- aggregation (pull, CSR); 2-edge unrolled, packed indices ----------------
__global__ void k_gather(const unsigned short* __restrict__ h, const float* __restrict__ sc,
                         const float* __restrict__ sh, int relu,
                         const int* __restrict__ row_ptr, const int2* __restrict__ edges,
                         const unsigned short* __restrict__ eec,
                         unsigned short* __restrict__ agg,
                         float* __restrict__ stz, int stzN) {
    if (blockIdx.x == 0) {
        for (int i = threadIdx.x; i < stzN; i += 256) stz[i] = 0.f;
    }
    unsigned int idx = blockIdx.x * 256u + threadIdx.x;  // N*40 chunks of 8 cols
    if (idx >= (unsigned int)NN * 40) return;
    unsigned int m = idx / 40;
    unsigned int j = idx % 40;
    int c0 = j * 8;
    bool aff = (sc != nullptr);
    float a[8] = {0, 0, 0, 0, 0, 0, 0, 0};
    float scv[8], shv[8];
    if (aff) {
#pragma unroll
        for (int i = 0; i < 8; i++) { scv[i] = sc[c0 + i]; shv[i] = sh[c0 + i]; }
    }
    int e0 = row_ptr[m], e1 = row_ptr[m + 1];
    int e = e0;
    // 2-edge unroll: issue both index loads, then all payload loads, before accumulating
    for (; e + 1 < e1; e += 2) {
        int2 ed0 = edges[e];
        int2 ed1 = edges[e + 1];
        uint4v hv0 = *(const uint4v*)(h + (size_t)ed0.x * DP + c0);
        uint4v hv1 = *(const uint4v*)(h + (size_t)ed1.x * DP + c0);
        uint4v ev0 = *(const uint4v*)(eec + (size_t)ed0.y * DP + c0);
        uint4v ev1 = *(const uint4v*)(eec + (size_t)ed1.y * DP + c0);
        const unsigned short* hp0 = (const unsigned short*)&hv0;
        const unsigned short* hp1 = (const unsigned short*)&hv1;
        const unsigned short* ep0 = (const unsigned short*)&ev0;
        const unsigned short* ep1 = (const unsigned short*)&ev1;
#pragma unroll
        for (int i = 0; i < 8; i++) {
            float f0 = h2f(hp0[i]);
            float f1 = h2f(hp1[i]);
            if (aff) {
                f0 = scv[i] * f0 + shv[i];
                f1 = scv[i] * f1 + shv[i];
                if (relu) { f0 = fmaxf(f0, 0.f); f1 = fmaxf(f1, 0.f); }
            }
            a[i] += f0 + h2f(ep0[i]);
            a[i] += f1 + h2f(ep1[i]);
        }
    }
    if (e < e1) {
        int2 ed = edges[e];
        uint4v hv = *(const uint4v*)(h + (size_t)ed.x * DP + c0);
        uint4v ev = *(const uint4v*)(eec + (size_t)ed.y * DP + c0);
        const unsigned short* hp = (const unsigned short*)&hv;
        const unsigned short* ep = (const unsigned short*)&ev;
#pragma unroll
        for (int i = 0; i < 8; i++) {
            float f = h2f(hp[i]);
            if (aff) {
                f = scv[i] * f + shv[i];
                if (relu) f = fmaxf(f, 0.f);
            }
            a[i] += f + h2f(ep[i]);
        }
    }
    unsigned short o[8];
#pragma unroll
    for (int i = 0; i < 8; i++) o[i] = f2h(a[i]);
    *(uint4v*)(agg + (size_t)m * DP + c0) = *(const uint4v*)o;
}

// ---------------- k_gemm_r4: reg-staged A + affine fold (142 us) ----------------
#define TLD 328
__launch_bounds__(512, 2)
__global__ void k_gemm_r4(const unsigned short* __restrict__ A, int lda, int kIters,
                          const unsigned short* __restrict__ scH,
                          const unsigned short* __restrict__ shH,
                          const unsigned short* __restrict__ B,
                          unsigned short* __restrict__ C, int ldc,
                          float* __restrict__ stats, int statN) {
    __shared__ unsigned short smem[128 * 64 + 320 * 64];
    unsigned short* As = smem;
    unsigned short* Bs = smem + 128 * 64;
    int tid = threadIdx.x;
    int lane = tid & 63, wid = tid >> 6;
    int wm = wid >> 2, wn = wid & 3;
    int m0 = blockIdx.y * 128;
    int n0 = blockIdx.x * 320;
    const unsigned short* Bb = B + (size_t)n0 * lda;

    int srow = tid >> 2;
    int sc16 = tid & 3;
    int swz = srow & 7;
    const unsigned short* aRow = A + (size_t)(m0 + srow) * lda;
    int brow8 = lane >> 3;
    int bc16 = (lane & 7) ^ brow8;

    f32x4 acc[4][5] = {};

    for (int kt = 0; kt < kIters; ++kt) {
        int k0 = kt * 64;
#pragma unroll
        for (int j = 0; j < 5; ++j) {
            int chunk = wid * 5 + j;
            int n = chunk * 8 + brow8;
            const unsigned short* g = Bb + (size_t)n * lda + k0 + bc16 * 8;
            __builtin_amdgcn_global_load_lds(
                (const __attribute__((address_space(1))) unsigned int*)g,
                (__attribute__((address_space(3))) unsigned int*)&Bs[chunk * 512], 16, 0, 0);
        }
        uint4v v0 = *(const uint4v*)(aRow + k0 + sc16 * 8);
        uint4v v1 = *(const uint4v*)(aRow + k0 + (sc16 + 4) * 8);
        if (scH) {
            f16x8 a0 = *(f16x8*)&v0, a1 = *(f16x8*)&v1;
            f16x8 s0 = *(const f16x8*)&scH[k0 + sc16 * 8];
            f16x8 h0 = *(const f16x8*)&shH[k0 + sc16 * 8];
            f16x8 s1 = *(const f16x8*)&scH[k0 + (sc16 + 4) * 8];
            f16x8 h1 = *(const f16x8*)&shH[k0 + (sc16 + 4) * 8];
#pragma unroll
            for (int i = 0; i < 8; i++) {
                _Float16 t0 = a0[i] * s0[i] + h0[i];
                _Float16 t1 = a1[i] * s1[i] + h1[i];
                a0[i] = t0 > (_Float16)0 ? t0 : (_Float16)0;
                a1[i] = t1 > (_Float16)0 ? t1 : (_Float16)0;
            }
            v0 = *(uint4v*)&a0;
            v1 = *(uint4v*)&a1;
        }
        *(uint4v*)&As[srow * 64 + ((sc16 ^ swz) * 8)] = v0;
        *(uint4v*)&As[srow * 64 + (((sc16 + 4) ^ swz) * 8)] = v1;
        __syncthreads();
        __builtin_amdgcn_s_setprio(1);
#pragma unroll
        for (int ks = 0; ks < 2; ++ks) {
            f16x8 af[4];
#pragma unroll
            for (int mf = 0; mf < 4; ++mf) {
                int ra = wm * 64 + mf * 16 + (lane & 15);
                int c16 = (ks * 4 + (lane >> 4)) ^ (ra & 7);
                af[mf] = *(const f16x8*)&As[ra * 64 + c16 * 8];
            }
#pragma unroll
            for (int nf = 0; nf < 5; ++nf) {
                int rb = wn * 80 + nf * 16 + (lane & 15);
                int c16 = (ks * 4 + (lane >> 4)) ^ (rb & 7);
                f16x8 bg = *(const f16x8*)&Bs[rb * 64 + c16 * 8];
#pragma unroll
                for (int mf = 0; mf < 4; ++mf)
                    acc[mf][nf] = __builtin_amdgcn_mfma_f32_16x16x32_f16(af[mf], bg, acc[mf][nf], 0, 0, 0);
            }
        }
        __builtin_amdgcn_s_setprio(0);
        __syncthreads();
    }

#pragma unroll
    for (int nf = 0; nf < 5; ++nf) {
        int col = n0 + wn * 80 + nf * 16 + (lane & 15);
        float s = 0.f, ss = 0.f;
#pragma unroll
        for (int mf = 0; mf < 4; ++mf) {
#pragma unroll
            for (int i = 0; i < 4; ++i) {
                float vr = h2f(f2h(acc[mf][nf][i]));
                s += vr;
                ss += vr * vr;
            }
        }
        s += __shfl_xor(s, 16); s += __shfl_xor(s, 32);
        ss += __shfl_xor(ss, 16); ss += __shfl_xor(ss, 32);
        if (lane < 16) {
            atomicAdd(&stats[col], s);
            atomicAdd(&stats[statN + col], ss);
        }
    }

    unsigned short* T = smem;
#pragma unroll
    for (int half = 0; half < 2; ++half) {
        __syncthreads();
        if (wm == half) {
#pragma unroll
            for (int nf = 0; nf < 5; ++nf) {
                int col = wn * 80 + nf * 16 + (lane & 15);
#pragma unroll
                for (int mf = 0; mf < 4; ++mf) {
                    int r = mf * 16 + ((lane >> 4) << 2);
#pragma unroll
                    for (int i = 0; i < 4; ++i)
                        T[(r + i) * TLD + col] = f2h(acc[mf][nf][i]);
                }
            }
        }
        __syncthreads();
        int rowbase = m0 + half * 64;
#pragma unroll
        for (int p = 0; p < 5; ++p) {
            int cid = p * 512 + tid;
            int r = cid / 40, c16 = cid % 40;
            uint4v v = *(const uint4v*)&T[r * TLD + c16 * 8];
            *(uint4v*)&C[(size_t)(rowbase + r) * ldc + n0 + c16 * 8] = v;
        }
    }
}

// ---------------- k_gemm_dma: A via global_load_lds (142 us) ----------------
__launch_bounds__(512, 2)
__global__ void k_gemm_dma(const unsigned short* __restrict__ A, int lda, int kIters,
                           const unsigned short* __restrict__ B,
                           unsigned short* __restrict__ C, int ldc,
                           float* __restrict__ stats, int statN) {
    __shared__ unsigned short smem[128 * 64 + 320 * 64];
    unsigned short* As = smem;
    unsigned short* Bs = smem + 128 * 64;
    int tid = threadIdx.x;
    int lane = tid & 63, wid = tid >> 6;
    int wm = wid >> 2, wn = wid & 3;
    int m0 = blockIdx.y * 128;
    int n0 = blockIdx.x * 320;
    const unsigned short* Bb = B + (size_t)n0 * lda;
    const unsigned short* Ab = A + (size_t)m0 * lda;

    int brow8 = lane >> 3;
    int bc16 = (lane & 7) ^ brow8;

    f32x4 acc[4][5] = {};

    for (int kt = 0; kt < kIters; ++kt) {
        int k0 = kt * 64;
#pragma unroll
        for (int j = 0; j < 5; ++j) {
            int chunk = wid * 5 + j;
            int n = chunk * 8 + brow8;
            const unsigned short* g = Bb + (size_t)n * lda + k0 + bc16 * 8;
            __builtin_amdgcn_global_load_lds(
                (const __attribute__((address_space(1))) unsigned int*)g,
                (__attribute__((address_space(3))) unsigned int*)&Bs[chunk * 512], 16, 0, 0);
        }
#pragma unroll
        for (int j = 0; j < 2; ++j) {
            int chunk = wid * 2 + j;
            int row = chunk * 8 + brow8;
            const unsigned short* g = Ab + (size_t)row * lda + k0 + bc16 * 8;
            __builtin_amdgcn_global_load_lds(
                (const __attribute__((address_space(1))) unsigned int*)g,
                (__attribute__((address_space(3))) unsigned int*)&As[chunk * 512], 16, 0, 0);
        }
        __syncthreads();
        __builtin_amdgcn_s_setprio(1);
#pragma unroll
        for (int ks = 0; ks < 2; ++ks) {
            f16x8 af[4];
#pragma unroll
            for (int mf = 0; mf < 4; ++mf) {
                int ra = wm * 64 + mf * 16 + (lane & 15);
                int c16 = (ks * 4 + (lane >> 4)) ^ (ra & 7);
                af[mf] = *(const f16x8*)&As[ra * 64 + c16 * 8];
            }
#pragma unroll
            for (int nf = 0; nf < 5; ++nf) {
                int rb = wn * 80 + nf * 16 + (lane & 15);
                int c16 = (ks * 4 + (lane >> 4)) ^ (rb & 7);
                f16x8 bg = *(const f16x8*)&Bs[rb * 64 + c16 * 8];
#pragma unroll
                for (int mf = 0; mf < 4; ++mf)
                    acc[mf][nf] = __builtin_amdgcn_mfma_f32_16x16x32_f16(af[mf], bg, acc[mf][nf], 0, 0, 0);
            }
        }
        __builtin_amdgcn_s_setprio(0);
        __syncthreads();
    }

#pragma unroll
    for (int nf = 0; nf < 5; ++nf) {
        int col = n0 + wn * 80 + nf * 16 + (lane & 15);
        float s = 0.f, ss = 0.f;
#pragma unroll
        for (int mf = 0; mf < 4; ++mf) {
#pragma unroll
            for (int i = 0; i < 4; ++i) {
                float vr = h2f(f2h(acc[mf][nf][i]));
                s += vr;
                ss += vr * vr;
            }
        }
        s += __shfl_xor(s, 16); s += __shfl_xor(s, 32);
        ss += __shfl_xor(ss, 16); ss += __shfl_xor(ss, 32);
        if (lane < 16) {
            atomicAdd(&stats[col], s);
            atomicAdd(&stats[statN + col], ss);
        }
    }

    unsigned short* T = smem;
#pragma unroll
    for (int half = 0; half < 2; ++half) {
        __syncthreads();
        if (wm == half) {
#pragma unroll
            for (int nf = 0; nf < 5; ++nf) {
                int col = wn * 80 + nf * 16 + (lane & 15);
#pragma unroll
                for (int mf = 0; mf < 4; ++mf) {
                    int r = mf * 16 + ((lane >> 4) << 2);
#pragma unroll
                    for (int i = 0; i < 4; ++i)
                        T[(r + i) * TLD + col] = f2h(acc[mf][nf][i]);
                }
            }
        }
        __syncthreads();
        int rowbase = m0 + half * 64;
#pragma unroll
        for (int p = 0; p < 5; ++p) {
            int cid = p * 512 + tid;
            int r = cid / 40, c16 = cid % 40;
            uint4v v = *(const uint4v*)&T[r * TLD + c16 * 8];
            *(uint4v*)&C[(size_t)(rowbase + r) * ldc + n0 + c16 * 8] = v;
        }
    }
}

// ---------------- BN scale/shift from stats; optionally zeros the next stats buffer ----------------
__global__ void k_bnprep(const float* __restrict__ stats, int statN, int realN,
                         const float* __restrict__ g, const float* __restrict__ b,
                         float* __restrict__ sc, float* __restrict__ sh,
                         unsigned short* __restrict__ scH, unsigned short* __restrict__ shH,
                         float* __restrict__ zbuf, int zn) {
    int n = blockIdx.x * 256 + threadIdx.x;
    if (n < zn) zbuf[n] = 0.f;
    if (n >= statN) return;
    float scv = 0.f, shv = 0.f;
    if (n < realN) {
        float mu = stats[n] * (1.f / NN);
        float var = stats[statN + n] * (1.f / NN) - mu * mu;
        var = fmaxf(var, 0.f);
        float rs = rsqrtf(var + BN_EPS);
        scv = g[n] * rs;
        shv = b[n] - mu * scv;
    }
    sc[n] = scv;
    sh[n] = shv;
    scH[n] = f2h(scv);
    shH[n] = f2h(shv);
}

// ---------------- final output: vectorized x4 (300 = 75 x 4, rows float4-aligned) ----------------
__global__ void k_out(const unsigned short* __restrict__ u2, const float* __restrict__ sc,
                      const float* __restrict__ sh, float* __restrict__ out) {
    unsigned int idx = blockIdx.x * 256u + threadIdx.x;
    if (idx >= (unsigned int)NN * 75) return;
    unsigned int n = idx / 75, q = idx % 75;
    int d = q * 4;
    u16x4 hv = *(const u16x4*)(u2 + (size_t)n * DP + d);
    f32x4 o;
#pragma unroll
    for (int i = 0; i < 4; ++i)
        o[i] = sc[d + i] * h2f(hv[i]) + sh[d + i];
    *(f32x4*)(out + (size_t)n * DD + d) = o;
}

extern "C" void kernel_launch(void* const* d_in, const int* in_sizes, int n_in,
                              void* d_out, int out_size, void* d_ws, size_t ws_size,
                              hipStream_t stream) {
    const int* x = (const int*)d_in[0];
    const int* ei = (const int*)d_in[1];
    const int* ea = (const int*)d_in[2];
    const float* xe1 = (const float*)d_in[3];
    const float* xe2 = (const float*)d_in[4];
    const float* ee1 = (const float*)d_in[5];
    const float* ee2 = (const float*)d_in[6];
    const float* W1 = (const float*)d_in[7];
    const float* bn1g = (const float*)d_in[9];
    const float* bn1b = (const float*)d_in[10];
    const float* W2 = (const float*)d_in[11];
    const float* bng = (const float*)d_in[13];
    const float* bnb = (const float*)d_in[14];
    float* out = (float*)d_out;

    char* ws = (char*)d_ws;
    size_t off = 0;
    auto alloc = [&](size_t bytes) -> void* {
        void* p = ws + off;
        off += (bytes + 255) & ~(size_t)255;
        return p;
    };
    unsigned short* hbuf = (unsigned short*)alloc((size_t)NN * DP * 2);   // h0 / u2
    unsigned short* agg  = (unsigned short*)alloc((size_t)NN * DP * 2);
    unsigned short* u1   = (unsigned short*)alloc((size_t)NN * D2P * 2);
    unsigned short* W1t  = (unsigned short*)alloc((size_t)NL * D2P * DP * 2);
    unsigned short* W2t  = (unsigned short*)alloc((size_t)NL * DP * D2P * 2);
    unsigned short* eec  = (unsigned short*)alloc((size_t)NL * 15 * DP * 2);
    int* row_ptr = (int*)alloc((size_t)(NN + 1) * 4);
    int* cursor  = (int*)alloc((size_t)NN * 4);
    int* counts  = (int*)alloc((size_t)NN * 4);
    int2* edges  = (int2*)alloc((size_t)NE * 8);
    int* partial  = (int*)alloc(512 * 4);
    int* partial2 = (int*)alloc(512 * 4);
    float* stats1 = (float*)alloc(2 * D2P * 4);
    float* stats2 = (float*)alloc(2 * DP * 4);
    float* sc1 = (float*)alloc(D2P * 4);
    float* sh1 = (float*)alloc(D2P * 4);
    float* sc2 = (float*)alloc(DP * 4);
    float* sh2 = (float*)alloc(DP * 4);
    unsigned short* scH1 = (unsigned short*)alloc(D2P * 2);
    unsigned short* shH1 = (unsigned short*)alloc(D2P * 2);
    unsigned short* scH2 = (unsigned short*)alloc(DP * 2);
    unsigned short* shH2 = (unsigned short*)alloc(DP * 2);

    // prep
    k_w1t<<<NL * D2P * DP / 256, 256, 0, stream>>>(W1, W1t);
    k_w2t<<<NL * DP * D2P / 256, 256, 0, stream>>>(W2, W2t);
    k_eec<<<(NL * 15 * DP + 255) / 256, 256, 0, stream>>>(ee1, ee2, eec);
    k_h0<<<NN * DP / 256, 256, 0, stream>>>(x, xe1, xe2, hbuf);

    // CSR
    hipMemsetAsync(counts, 0, (size_t)NN * 4, stream);
    k_count<<<NE / 256, 256, 0, stream>>>(ei, counts);
    k_scan1<<<NN / 256, 256, 0, stream>>>(counts, partial);
    k_scan2<<<1, 512, 0, stream>>>(partial, partial2);
    k_scan3<<<NN / 256, 256, 0, stream>>>(counts, partial2, row_ptr, cursor);
    k_fill<<<NE / 256, 256, 0, stream>>>(ei, ea, cursor, edges);

    const unsigned short* hcur = hbuf;
    const float* scIn = nullptr;   // layer 0: identity (no affine)
    const float* shIn = nullptr;
    int reluIn = 0;
    for (int l = 0; l < NL; ++l) {
        // gather also zeros stats1 (block 0)
        k_gather<<<NN * 40 / 256, 256, 0, stream>>>(hcur, scIn, shIn, reluIn, row_ptr, edges,
                                                    eec + (size_t)l * 15 * DP, agg,
                                                    stats1, 2 * D2P);
        dim3 g1(D2P / 320, NN / 128);
        k_gemm_dma<<<g1, 512, 0, stream>>>(agg, DP, DP / 64,
                                           W1t + (size_t)l * D2P * DP, u1, D2P, stats1, D2P);
        // bnprep(stats1) also zeros stats2
        k_bnprep<<<(D2P + 255) / 256, 256, 0, stream>>>(stats1, D2P, D2, bn1g + (size_t)l * D2,
                                                        bn1b + (size_t)l * D2, sc1, sh1, scH1, shH1,
                                                        stats2, 2 * DP);
        dim3 g2(DP / 320, NN / 128);
        k_gemm_r4<<<g2, 512, 0, stream>>>(u1, D2P, D2P / 64, scH1, shH1,
                                          W2t + (size_t)l * DP * D2P, hbuf, DP, stats2, DP);
        k_bnprep<<<(DP + 255) / 256, 256, 0, stream>>>(stats2, DP, DD, bng + (size_t)l * DD,
                                                       bnb + (size_t)l * DD, sc2, sh2, scH2, shH2,
                                                       nullptr, 0);
        hcur = hbuf;
        scIn = sc2;
        shIn = sh2;
        reluIn = 1;
    }
    k_out<<<NN * 75 / 256, 256, 0, stream>>>(hbuf, sc2, sh2, out);
}